// Round 3
// baseline (2524.771 us; speedup 1.0000x reference)
//
#include <hip/hip_runtime.h>

constexpr int T  = 2048;
constexpr int Dm = 1024;
constexpr int NH = 16;
constexpr int DH = 64;

// ---------------------------------------------------------------------------
// invfreq[c] = 10000^(-(c & ~1)/1024)   (AP[t,c] = sin/cos(t * invfreq[c]))
// ---------------------------------------------------------------------------
__global__ __launch_bounds__(256) void invfreq_kernel(float* __restrict__ invfreq) {
    int c = blockIdx.x * 256 + threadIdx.x;
    if (c < T) {
        float e = (float)(c & ~1) / (float)Dm;
        invfreq[c] = powf(10000.0f, -e);
    }
}

// ---------------------------------------------------------------------------
// Generic C[m, 0..63] = sum_k A[m,k] * B[k, 0..63], tiled 64x64, 256 threads.
// z = blockIdx.y selects head via pointer strides. Used for QKV and PV.
// ---------------------------------------------------------------------------
__global__ __launch_bounds__(256) void gemm_n64(
    const float* __restrict__ Abase, long a_zs, int lda,
    const float* __restrict__ Bbase, long b_zs,
    float* __restrict__ Cbase, long c_zs, int ldc, int Kdim)
{
    __shared__ float As[64][20];   // pad 20: fp32x4-aligned rows, 2-way bank max
    __shared__ float Bs[16][64];

    const int z = blockIdx.y;
    const float* A = Abase + (long)z * a_zs;
    const float* B = Bbase + (long)z * b_zs;
    float* C = Cbase + (long)z * c_zs;

    const int m0 = blockIdx.x * 64;
    const int tid = threadIdx.x;
    const int tx = tid & 15, ty = tid >> 4;
    const int arow = tid >> 2, aq = (tid & 3) * 4;
    const int bkk = tid >> 4, bq = (tid & 15) * 4;

    float acc[4][4] = {};
    for (int kb = 0; kb < Kdim; kb += 16) {
        float4 av = *(const float4*)(A + (long)(m0 + arow) * lda + kb + aq);
        float4 bv = *(const float4*)(B + (long)(kb + bkk) * 64 + bq);
        *(float4*)&As[arow][aq] = av;
        *(float4*)&Bs[bkk][bq]  = bv;
        __syncthreads();
        #pragma unroll
        for (int kk = 0; kk < 16; ++kk) {
            float a[4];
            #pragma unroll
            for (int i = 0; i < 4; ++i) a[i] = As[ty*4+i][kk];
            float4 b4 = *(const float4*)&Bs[kk][tx*4];
            float b[4] = {b4.x, b4.y, b4.z, b4.w};
            #pragma unroll
            for (int i = 0; i < 4; ++i)
                #pragma unroll
                for (int j = 0; j < 4; ++j)
                    acc[i][j] = fmaf(a[i], b[j], acc[i][j]);
        }
        __syncthreads();
    }
    #pragma unroll
    for (int i = 0; i < 4; ++i) {
        float4 o = make_float4(acc[i][0], acc[i][1], acc[i][2], acc[i][3]);
        *(float4*)(C + (long)(m0 + ty*4 + i) * ldc + tx*4) = o;
    }
}

// ---------------------------------------------------------------------------
// S[t,s] = Q[h,t,:]·K[h,s,:] + AP[t,s]   (K-dim = 64, fully staged)
// ---------------------------------------------------------------------------
__global__ __launch_bounds__(256) void score_kernel(
    const float* __restrict__ Qall, const float* __restrict__ Kall,
    float* __restrict__ Sbase, long s_zs, int h0,
    const float* __restrict__ invfreq)
{
    __shared__ float Qs[64][65];   // ld 65: conflict-free strided row reads
    __shared__ float Ks[64][65];

    const int z = blockIdx.z;
    const int h = h0 + z;
    const float* Qh = Qall + (long)h * T * DH;
    const float* Kh = Kall + (long)h * T * DH;
    float* S = Sbase + (long)z * s_zs;

    const int t0 = blockIdx.y * 64, s0 = blockIdx.x * 64;
    const int tid = threadIdx.x;
    const int tx = tid & 15, ty = tid >> 4;

    #pragma unroll
    for (int it = 0; it < 4; ++it) {
        int idx = it * 256 + tid;
        int row = idx >> 4, q = (idx & 15) * 4;
        float4 qv = *(const float4*)(Qh + (long)(t0 + row) * DH + q);
        float4 kv = *(const float4*)(Kh + (long)(s0 + row) * DH + q);
        Qs[row][q] = qv.x; Qs[row][q+1] = qv.y; Qs[row][q+2] = qv.z; Qs[row][q+3] = qv.w;
        Ks[row][q] = kv.x; Ks[row][q+1] = kv.y; Ks[row][q+2] = kv.z; Ks[row][q+3] = kv.w;
    }
    __syncthreads();

    float acc[4][4] = {};
    #pragma unroll 8
    for (int kk = 0; kk < 64; ++kk) {
        float a[4], b[4];
        #pragma unroll
        for (int i = 0; i < 4; ++i) a[i] = Qs[ty*4+i][kk];
        #pragma unroll
        for (int j = 0; j < 4; ++j) b[j] = Ks[tx*4+j][kk];
        #pragma unroll
        for (int i = 0; i < 4; ++i)
            #pragma unroll
            for (int j = 0; j < 4; ++j)
                acc[i][j] = fmaf(a[i], b[j], acc[i][j]);
    }

    float ifr[4];
    #pragma unroll
    for (int j = 0; j < 4; ++j) ifr[j] = invfreq[s0 + tx*4 + j];

    #pragma unroll
    for (int i = 0; i < 4; ++i) {
        int t = t0 + ty*4 + i;
        float o[4];
        #pragma unroll
        for (int j = 0; j < 4; ++j) {
            float angle = (float)t * ifr[j];
            float ap = (j & 1) ? cosf(angle) : sinf(angle);  // s0+tx*4 is even
            o[j] = acc[i][j] + ap;
        }
        float4 ov = make_float4(o[0], o[1], o[2], o[3]);
        *(float4*)(S + (long)t * T + s0 + tx*4) = ov;
    }
}

// ---------------------------------------------------------------------------
// In-place row softmax over 2048 elements. One block (256 thr) per row.
// ---------------------------------------------------------------------------
__global__ __launch_bounds__(256) void softmax_kernel(float* __restrict__ Sbase, long s_zs)
{
    float* S = Sbase + (long)blockIdx.y * s_zs + (long)blockIdx.x * T;
    const int tid = threadIdx.x;
    const int wid = tid >> 6, lane = tid & 63;

    float4 v0 = *(const float4*)(S + tid*8);
    float4 v1 = *(const float4*)(S + tid*8 + 4);

    float m = fmaxf(fmaxf(fmaxf(v0.x, v0.y), fmaxf(v0.z, v0.w)),
                    fmaxf(fmaxf(v1.x, v1.y), fmaxf(v1.z, v1.w)));
    #pragma unroll
    for (int o = 32; o > 0; o >>= 1) m = fmaxf(m, __shfl_xor(m, o));

    __shared__ float redm[4];
    __shared__ float reds[4];
    if (lane == 0) redm[wid] = m;
    __syncthreads();
    m = fmaxf(fmaxf(redm[0], redm[1]), fmaxf(redm[2], redm[3]));

    v0.x = expf(v0.x - m); v0.y = expf(v0.y - m); v0.z = expf(v0.z - m); v0.w = expf(v0.w - m);
    v1.x = expf(v1.x - m); v1.y = expf(v1.y - m); v1.z = expf(v1.z - m); v1.w = expf(v1.w - m);

    float s = v0.x + v0.y + v0.z + v0.w + v1.x + v1.y + v1.z + v1.w;
    #pragma unroll
    for (int o = 32; o > 0; o >>= 1) s += __shfl_xor(s, o);
    if (lane == 0) reds[wid] = s;
    __syncthreads();
    s = reds[0] + reds[1] + reds[2] + reds[3];

    float inv = 1.0f / s;
    v0.x *= inv; v0.y *= inv; v0.z *= inv; v0.w *= inv;
    v1.x *= inv; v1.y *= inv; v1.z *= inv; v1.w *= inv;
    *(float4*)(S + tid*8)     = v0;
    *(float4*)(S + tid*8 + 4) = v1;
}

// ---------------------------------------------------------------------------
// y_out[t,n] = sum_k Yc[t,k] * Wout[n,k]   (B transposed layout, N=1024)
// ---------------------------------------------------------------------------
__global__ __launch_bounds__(256) void gemm_out(
    const float* __restrict__ A, const float* __restrict__ Bt,
    float* __restrict__ C)
{
    __shared__ float As[64][20];
    __shared__ float Bs[16][68];   // [kk][n], ld 68 keeps fp32x4 reads aligned

    const int m0 = blockIdx.y * 64, n0 = blockIdx.x * 64;
    const int tid = threadIdx.x;
    const int tx = tid & 15, ty = tid >> 4;
    const int arow = tid >> 2, aq = (tid & 3) * 4;
    const int bn = tid >> 2,  bq = (tid & 3) * 4;

    float acc[4][4] = {};
    for (int kb = 0; kb < Dm; kb += 16) {
        float4 av = *(const float4*)(A  + (long)(m0 + arow) * Dm + kb + aq);
        float4 bv = *(const float4*)(Bt + (long)(n0 + bn)  * Dm + kb + bq);
        *(float4*)&As[arow][aq] = av;
        Bs[bq+0][bn] = bv.x; Bs[bq+1][bn] = bv.y; Bs[bq+2][bn] = bv.z; Bs[bq+3][bn] = bv.w;
        __syncthreads();
        #pragma unroll
        for (int kk = 0; kk < 16; ++kk) {
            float a[4];
            #pragma unroll
            for (int i = 0; i < 4; ++i) a[i] = As[ty*4+i][kk];
            float4 b4 = *(const float4*)&Bs[kk][tx*4];
            float b[4] = {b4.x, b4.y, b4.z, b4.w};
            #pragma unroll
            for (int i = 0; i < 4; ++i)
                #pragma unroll
                for (int j = 0; j < 4; ++j)
                    acc[i][j] = fmaf(a[i], b[j], acc[i][j]);
        }
        __syncthreads();
    }
    #pragma unroll
    for (int i = 0; i < 4; ++i) {
        float4 o = make_float4(acc[i][0], acc[i][1], acc[i][2], acc[i][3]);
        *(float4*)(C + (long)(m0 + ty*4 + i) * Dm + n0 + tx*4) = o;
    }
}

// ---------------------------------------------------------------------------
extern "C" void kernel_launch(void* const* d_in, const int* in_sizes, int n_in,
                              void* d_out, int out_size, void* d_ws, size_t ws_size,
                              hipStream_t stream)
{
    const float* x    = (const float*)d_in[0];   // [T, Dm]
    const float* Wq   = (const float*)d_in[1];   // [NH, Dm, DH]
    const float* Wk   = (const float*)d_in[2];
    const float* Wv   = (const float*)d_in[3];
    const float* Wout = (const float*)d_in[4];   // [Dm, Dm]

    float* out      = (float*)d_out;
    float* y_out    = out;                       // [T, Dm]
    float* attn_out = out + (long)T * Dm;        // [T, T]  (head 15 attention)

    float* ws      = (float*)d_ws;
    float* invfreq = ws;                                   // 2048
    float* Qb      = invfreq + 2048;                       // [NH, T, DH]
    float* Kb      = Qb + (long)NH * T * DH;
    float* Vb      = Kb + (long)NH * T * DH;
    float* Yc      = Vb + (long)NH * T * DH;               // [T, Dm] concat heads
    float* Sws     = Yc + (long)T * Dm;                    // [15, T, T] (Path A)

    size_t baseFloats = (size_t)(Sws - ws);
    size_t needA = (baseFloats + (size_t)15 * T * T) * sizeof(float);
    bool bigws = ws_size >= needA;

    invfreq_kernel<<<dim3(8), dim3(256), 0, stream>>>(invfreq);

    // QKV projections: per head, x[T,Dm] @ W[h][Dm,DH]
    {
        dim3 g(T / 64, NH);
        gemm_n64<<<g, 256, 0, stream>>>(x, 0L, Dm, Wq, (long)Dm * DH, Qb, (long)T * DH, DH, Dm);
        gemm_n64<<<g, 256, 0, stream>>>(x, 0L, Dm, Wk, (long)Dm * DH, Kb, (long)T * DH, DH, Dm);
        gemm_n64<<<g, 256, 0, stream>>>(x, 0L, Dm, Wv, (long)Dm * DH, Vb, (long)T * DH, DH, Dm);
    }

    if (bigws) {
        // heads 0..14 -> ws, head 15 -> d_out attn region (it's the 2nd output)
        score_kernel<<<dim3(T/64, T/64, 15), 256, 0, stream>>>(Qb, Kb, Sws, (long)T * T, 0, invfreq);
        score_kernel<<<dim3(T/64, T/64, 1),  256, 0, stream>>>(Qb, Kb, attn_out, 0L, 15, invfreq);
        softmax_kernel<<<dim3(T, 15), 256, 0, stream>>>(Sws, (long)T * T);
        softmax_kernel<<<dim3(T, 1),  256, 0, stream>>>(attn_out, 0L);
        gemm_n64<<<dim3(T/64, 15), 256, 0, stream>>>(Sws, (long)T * T, T,
                                                     Vb, (long)T * DH,
                                                     Yc, 64L, Dm, T);
        gemm_n64<<<dim3(T/64, 1), 256, 0, stream>>>(attn_out, 0L, T,
                                                    Vb + (long)15 * T * DH, 0L,
                                                    Yc + 15 * 64, 0L, Dm, T);
    } else {
        // sequential per-head, reusing the d_out attn region as score scratch;
        // head 15 runs last so its attention remains in place.
        for (int h = 0; h < NH; ++h) {
            score_kernel<<<dim3(T/64, T/64, 1), 256, 0, stream>>>(Qb, Kb, attn_out, 0L, h, invfreq);
            softmax_kernel<<<dim3(T, 1), 256, 0, stream>>>(attn_out, 0L);
            gemm_n64<<<dim3(T/64, 1), 256, 0, stream>>>(attn_out, 0L, T,
                                                        Vb + (long)h * T * DH, 0L,
                                                        Yc + h * 64, 0L, Dm, T);
        }
    }

    // Output projection: y = Yc @ Wout^T
    gemm_out<<<dim3(Dm / 64, T / 64), 256, 0, stream>>>(Yc, Wout, y_out);
}

// Round 7
// 721.621 us; speedup vs baseline: 3.4987x; 3.4987x over previous
//
#include <hip/hip_runtime.h>
#include <math.h>

constexpr int T  = 2048;
constexpr int Dm = 1024;
constexpr int NH = 16;
constexpr int DH = 64;

// ---------------------------------------------------------------------------
// invfreq[c] = 10000^(-(c & ~1)/1024)   (AP[t,c] = sin/cos(t * invfreq[c]))
// ---------------------------------------------------------------------------
__global__ __launch_bounds__(256) void invfreq_kernel(float* __restrict__ invfreq) {
    int c = blockIdx.x * 256 + threadIdx.x;
    if (c < T) {
        float e = (float)(c & ~1) / (float)Dm;
        invfreq[c] = powf(10000.0f, -e);
    }
}

// ---------------------------------------------------------------------------
// Generic C[m, 0..63] = sum_k A[m,k] * B[k, 0..63], tiled 64x64, 256 threads.
// z = blockIdx.y selects head via pointer strides. Used for QKV projections.
// ---------------------------------------------------------------------------
__global__ __launch_bounds__(256) void gemm_n64(
    const float* __restrict__ Abase, long a_zs, int lda,
    const float* __restrict__ Bbase, long b_zs,
    float* __restrict__ Cbase, long c_zs, int ldc, int Kdim)
{
    __shared__ float As[64][20];
    __shared__ float Bs[16][64];

    const int z = blockIdx.y;
    const float* A = Abase + (long)z * a_zs;
    const float* B = Bbase + (long)z * b_zs;
    float* C = Cbase + (long)z * c_zs;

    const int m0 = blockIdx.x * 64;
    const int tid = threadIdx.x;
    const int tx = tid & 15, ty = tid >> 4;
    const int arow = tid >> 2, aq = (tid & 3) * 4;
    const int bkk = tid >> 4, bq = (tid & 15) * 4;

    float acc[4][4] = {};
    for (int kb = 0; kb < Kdim; kb += 16) {
        float4 av = *(const float4*)(A + (long)(m0 + arow) * lda + kb + aq);
        float4 bv = *(const float4*)(B + (long)(kb + bkk) * 64 + bq);
        *(float4*)&As[arow][aq] = av;
        *(float4*)&Bs[bkk][bq]  = bv;
        __syncthreads();
        #pragma unroll
        for (int kk = 0; kk < 16; ++kk) {
            float a[4];
            #pragma unroll
            for (int i = 0; i < 4; ++i) a[i] = As[ty*4+i][kk];
            float4 b4 = *(const float4*)&Bs[kk][tx*4];
            float b[4] = {b4.x, b4.y, b4.z, b4.w};
            #pragma unroll
            for (int i = 0; i < 4; ++i)
                #pragma unroll
                for (int j = 0; j < 4; ++j)
                    acc[i][j] = fmaf(a[i], b[j], acc[i][j]);
        }
        __syncthreads();
    }
    #pragma unroll
    for (int i = 0; i < 4; ++i) {
        float4 o = make_float4(acc[i][0], acc[i][1], acc[i][2], acc[i][3]);
        *(float4*)(C + (long)(m0 + ty*4 + i) * ldc + tx*4) = o;
    }
}

// ---------------------------------------------------------------------------
// Fused flash attention: per block = (one head, 64 Q rows). Online softmax.
// Grid (T/64, NH) = 512 blocks -> 2 blocks/CU co-resident (LDS 67 KB).
// Computes Yc[t, h*64 + c] for all heads; S never materialized.
// ---------------------------------------------------------------------------
__global__ __launch_bounds__(256) void flash_kernel(
    const float* __restrict__ Qall, const float* __restrict__ Kall,
    const float* __restrict__ Vall, float* __restrict__ Yc,
    const float* __restrict__ invfreq)
{
    __shared__ float Qs[64][65];   // pad 65: scalar reads (r+kk)%32 -> <=2-way
    __shared__ float Ks[64][65];
    __shared__ float Vs[64][65];
    __shared__ float Ps[64][68];   // pad 68: float4 writes, scalar reads 2-way

    const int h  = blockIdx.y;
    const int t0 = blockIdx.x * 64;
    const float* Qh = Qall + (long)h * T * DH;
    const float* Kh = Kall + (long)h * T * DH;
    const float* Vh = Vall + (long)h * T * DH;

    const int tid = threadIdx.x;
    const int tx = tid & 15, ty = tid >> 4;

    // stage Q tile once
    #pragma unroll
    for (int it = 0; it < 4; ++it) {
        int idx = it * 256 + tid;
        int row = idx >> 4, q = (idx & 15) * 4;
        float4 qv = *(const float4*)(Qh + (long)(t0 + row) * DH + q);
        Qs[row][q] = qv.x; Qs[row][q+1] = qv.y; Qs[row][q+2] = qv.z; Qs[row][q+3] = qv.w;
    }

    float m_run[4], l_run[4], o[4][4];
    #pragma unroll
    for (int i = 0; i < 4; ++i) {
        m_run[i] = -INFINITY; l_run[i] = 0.0f;
        #pragma unroll
        for (int j = 0; j < 4; ++j) o[i][j] = 0.0f;
    }

    for (int s0 = 0; s0 < T; s0 += 64) {
        __syncthreads();   // prev PV done reading Vs/Ps before restage
        #pragma unroll
        for (int it = 0; it < 4; ++it) {
            int idx = it * 256 + tid;
            int row = idx >> 4, q = (idx & 15) * 4;
            float4 kv = *(const float4*)(Kh + (long)(s0 + row) * DH + q);
            float4 vv = *(const float4*)(Vh + (long)(s0 + row) * DH + q);
            Ks[row][q] = kv.x; Ks[row][q+1] = kv.y; Ks[row][q+2] = kv.z; Ks[row][q+3] = kv.w;
            Vs[row][q] = vv.x; Vs[row][q+1] = vv.y; Vs[row][q+2] = vv.z; Vs[row][q+3] = vv.w;
        }
        __syncthreads();

        // S tile = Q K^T
        float acc[4][4] = {};
        #pragma unroll 8
        for (int kk = 0; kk < 64; ++kk) {
            float a[4], b[4];
            #pragma unroll
            for (int i = 0; i < 4; ++i) a[i] = Qs[ty*4+i][kk];
            #pragma unroll
            for (int j = 0; j < 4; ++j) b[j] = Ks[tx*4+j][kk];
            #pragma unroll
            for (int i = 0; i < 4; ++i)
                #pragma unroll
                for (int j = 0; j < 4; ++j)
                    acc[i][j] = fmaf(a[i], b[j], acc[i][j]);
        }

        // + AP bias: AP[t,s] = sin/cos(t * invfreq[s]); (s0+tx*4) even -> j&1 picks
        float ifr[4];
        #pragma unroll
        for (int j = 0; j < 4; ++j) ifr[j] = invfreq[s0 + tx*4 + j];
        #pragma unroll
        for (int i = 0; i < 4; ++i) {
            float tf = (float)(t0 + ty*4 + i);
            #pragma unroll
            for (int j = 0; j < 4; ++j) {
                float angle = tf * ifr[j];
                acc[i][j] += (j & 1) ? cosf(angle) : sinf(angle);
            }
        }

        // online softmax update (rows spread over 16 lanes sharing ty)
        #pragma unroll
        for (int i = 0; i < 4; ++i) {
            float tm = fmaxf(fmaxf(acc[i][0], acc[i][1]), fmaxf(acc[i][2], acc[i][3]));
            #pragma unroll
            for (int msk = 8; msk > 0; msk >>= 1) tm = fmaxf(tm, __shfl_xor(tm, msk));
            float mnew  = fmaxf(m_run[i], tm);
            float alpha = expf(m_run[i] - mnew);   // first tile: exp(-inf)=0
            float p0 = expf(acc[i][0] - mnew);
            float p1 = expf(acc[i][1] - mnew);
            float p2 = expf(acc[i][2] - mnew);
            float p3 = expf(acc[i][3] - mnew);
            acc[i][0] = p0; acc[i][1] = p1; acc[i][2] = p2; acc[i][3] = p3;
            float rs = p0 + p1 + p2 + p3;
            #pragma unroll
            for (int msk = 8; msk > 0; msk >>= 1) rs += __shfl_xor(rs, msk);
            l_run[i] = l_run[i] * alpha + rs;
            m_run[i] = mnew;
            #pragma unroll
            for (int j = 0; j < 4; ++j) o[i][j] *= alpha;
            *(float4*)&Ps[ty*4+i][tx*4] = make_float4(p0, p1, p2, p3);
        }
        __syncthreads();

        // O += P V
        #pragma unroll 8
        for (int kk = 0; kk < 64; ++kk) {
            float pa[4], vb[4];
            #pragma unroll
            for (int i = 0; i < 4; ++i) pa[i] = Ps[ty*4+i][kk];
            #pragma unroll
            for (int j = 0; j < 4; ++j) vb[j] = Vs[kk][tx*4+j];
            #pragma unroll
            for (int i = 0; i < 4; ++i)
                #pragma unroll
                for (int j = 0; j < 4; ++j)
                    o[i][j] = fmaf(pa[i], vb[j], o[i][j]);
        }
    }

    #pragma unroll
    for (int i = 0; i < 4; ++i) {
        float inv = 1.0f / l_run[i];
        float4 ov = make_float4(o[i][0]*inv, o[i][1]*inv, o[i][2]*inv, o[i][3]*inv);
        *(float4*)(Yc + (long)(t0 + ty*4 + i) * Dm + h * DH + tx*4) = ov;
    }
}

// ---------------------------------------------------------------------------
// S[t,s] = Q[h,t,:]·K[h,s,:] + AP[t,s]  -- used only for head 15's attn output
// ---------------------------------------------------------------------------
__global__ __launch_bounds__(256) void score_kernel(
    const float* __restrict__ Qall, const float* __restrict__ Kall,
    float* __restrict__ Sbase, long s_zs, int h0,
    const float* __restrict__ invfreq)
{
    __shared__ float Qs[64][65];
    __shared__ float Ks[64][65];

    const int z = blockIdx.z;
    const int h = h0 + z;
    const float* Qh = Qall + (long)h * T * DH;
    const float* Kh = Kall + (long)h * T * DH;
    float* S = Sbase + (long)z * s_zs;

    const int t0 = blockIdx.y * 64, s0 = blockIdx.x * 64;
    const int tid = threadIdx.x;
    const int tx = tid & 15, ty = tid >> 4;

    #pragma unroll
    for (int it = 0; it < 4; ++it) {
        int idx = it * 256 + tid;
        int row = idx >> 4, q = (idx & 15) * 4;
        float4 qv = *(const float4*)(Qh + (long)(t0 + row) * DH + q);
        float4 kv = *(const float4*)(Kh + (long)(s0 + row) * DH + q);
        Qs[row][q] = qv.x; Qs[row][q+1] = qv.y; Qs[row][q+2] = qv.z; Qs[row][q+3] = qv.w;
        Ks[row][q] = kv.x; Ks[row][q+1] = kv.y; Ks[row][q+2] = kv.z; Ks[row][q+3] = kv.w;
    }
    __syncthreads();

    float acc[4][4] = {};
    #pragma unroll 8
    for (int kk = 0; kk < 64; ++kk) {
        float a[4], b[4];
        #pragma unroll
        for (int i = 0; i < 4; ++i) a[i] = Qs[ty*4+i][kk];
        #pragma unroll
        for (int j = 0; j < 4; ++j) b[j] = Ks[tx*4+j][kk];
        #pragma unroll
        for (int i = 0; i < 4; ++i)
            #pragma unroll
            for (int j = 0; j < 4; ++j)
                acc[i][j] = fmaf(a[i], b[j], acc[i][j]);
    }

    float ifr[4];
    #pragma unroll
    for (int j = 0; j < 4; ++j) ifr[j] = invfreq[s0 + tx*4 + j];

    #pragma unroll
    for (int i = 0; i < 4; ++i) {
        int t = t0 + ty*4 + i;
        float o[4];
        #pragma unroll
        for (int j = 0; j < 4; ++j) {
            float angle = (float)t * ifr[j];
            float ap = (j & 1) ? cosf(angle) : sinf(angle);
            o[j] = acc[i][j] + ap;
        }
        float4 ov = make_float4(o[0], o[1], o[2], o[3]);
        *(float4*)(S + (long)t * T + s0 + tx*4) = ov;
    }
}

// ---------------------------------------------------------------------------
// In-place row softmax over 2048 elements. One block (256 thr) per row.
// ---------------------------------------------------------------------------
__global__ __launch_bounds__(256) void softmax_kernel(float* __restrict__ Sbase, long s_zs)
{
    float* S = Sbase + (long)blockIdx.y * s_zs + (long)blockIdx.x * T;
    const int tid = threadIdx.x;
    const int wid = tid >> 6, lane = tid & 63;

    float4 v0 = *(const float4*)(S + tid*8);
    float4 v1 = *(const float4*)(S + tid*8 + 4);

    float m = fmaxf(fmaxf(fmaxf(v0.x, v0.y), fmaxf(v0.z, v0.w)),
                    fmaxf(fmaxf(v1.x, v1.y), fmaxf(v1.z, v1.w)));
    #pragma unroll
    for (int o = 32; o > 0; o >>= 1) m = fmaxf(m, __shfl_xor(m, o));

    __shared__ float redm[4];
    __shared__ float reds[4];
    if (lane == 0) redm[wid] = m;
    __syncthreads();
    m = fmaxf(fmaxf(redm[0], redm[1]), fmaxf(redm[2], redm[3]));

    v0.x = expf(v0.x - m); v0.y = expf(v0.y - m); v0.z = expf(v0.z - m); v0.w = expf(v0.w - m);
    v1.x = expf(v1.x - m); v1.y = expf(v1.y - m); v1.z = expf(v1.z - m); v1.w = expf(v1.w - m);

    float s = v0.x + v0.y + v0.z + v0.w + v1.x + v1.y + v1.z + v1.w;
    #pragma unroll
    for (int o = 32; o > 0; o >>= 1) s += __shfl_xor(s, o);
    if (lane == 0) reds[wid] = s;
    __syncthreads();
    s = reds[0] + reds[1] + reds[2] + reds[3];

    float inv = 1.0f / s;
    v0.x *= inv; v0.y *= inv; v0.z *= inv; v0.w *= inv;
    v1.x *= inv; v1.y *= inv; v1.z *= inv; v1.w *= inv;
    *(float4*)(S + tid*8)     = v0;
    *(float4*)(S + tid*8 + 4) = v1;
}

// ---------------------------------------------------------------------------
// y_out[t,n] = sum_k Yc[t,k] * Wout[n,k]   (B transposed layout, N=1024)
// ---------------------------------------------------------------------------
__global__ __launch_bounds__(256) void gemm_out(
    const float* __restrict__ A, const float* __restrict__ Bt,
    float* __restrict__ C)
{
    __shared__ float As[64][20];
    __shared__ float Bs[16][68];

    const int m0 = blockIdx.y * 64, n0 = blockIdx.x * 64;
    const int tid = threadIdx.x;
    const int tx = tid & 15, ty = tid >> 4;
    const int arow = tid >> 2, aq = (tid & 3) * 4;
    const int bn = tid >> 2,  bq = (tid & 3) * 4;

    float acc[4][4] = {};
    for (int kb = 0; kb < Dm; kb += 16) {
        float4 av = *(const float4*)(A  + (long)(m0 + arow) * Dm + kb + aq);
        float4 bv = *(const float4*)(Bt + (long)(n0 + bn)  * Dm + kb + bq);
        *(float4*)&As[arow][aq] = av;
        Bs[bq+0][bn] = bv.x; Bs[bq+1][bn] = bv.y; Bs[bq+2][bn] = bv.z; Bs[bq+3][bn] = bv.w;
        __syncthreads();
        #pragma unroll
        for (int kk = 0; kk < 16; ++kk) {
            float a[4];
            #pragma unroll
            for (int i = 0; i < 4; ++i) a[i] = As[ty*4+i][kk];
            float4 b4 = *(const float4*)&Bs[kk][tx*4];
            float b[4] = {b4.x, b4.y, b4.z, b4.w};
            #pragma unroll
            for (int i = 0; i < 4; ++i)
                #pragma unroll
                for (int j = 0; j < 4; ++j)
                    acc[i][j] = fmaf(a[i], b[j], acc[i][j]);
        }
        __syncthreads();
    }
    #pragma unroll
    for (int i = 0; i < 4; ++i) {
        float4 o = make_float4(acc[i][0], acc[i][1], acc[i][2], acc[i][3]);
        *(float4*)(C + (long)(m0 + ty*4 + i) * Dm + n0 + tx*4) = o;
    }
}

// ---------------------------------------------------------------------------
extern "C" void kernel_launch(void* const* d_in, const int* in_sizes, int n_in,
                              void* d_out, int out_size, void* d_ws, size_t ws_size,
                              hipStream_t stream)
{
    const float* x    = (const float*)d_in[0];   // [T, Dm]
    const float* Wq   = (const float*)d_in[1];   // [NH, Dm, DH]
    const float* Wk   = (const float*)d_in[2];
    const float* Wv   = (const float*)d_in[3];
    const float* Wout = (const float*)d_in[4];   // [Dm, Dm]

    float* out      = (float*)d_out;
    float* y_out    = out;                       // [T, Dm]
    float* attn_out = out + (long)T * Dm;        // [T, T]  (head 15 attention)

    float* ws      = (float*)d_ws;
    float* invfreq = ws;                                   // 2048
    float* Qb      = invfreq + 2048;                       // [NH, T, DH]
    float* Kb      = Qb + (long)NH * T * DH;
    float* Vb      = Kb + (long)NH * T * DH;
    float* Yc      = Vb + (long)NH * T * DH;               // [T, Dm] concat heads
    (void)ws_size;                                         // needs ~33.6 MB total

    invfreq_kernel<<<dim3(8), dim3(256), 0, stream>>>(invfreq);

    // QKV projections: per head, x[T,Dm] @ W[h][Dm,DH]
    {
        dim3 g(T / 64, NH);
        gemm_n64<<<g, 256, 0, stream>>>(x, 0L, Dm, Wq, (long)Dm * DH, Qb, (long)T * DH, DH, Dm);
        gemm_n64<<<g, 256, 0, stream>>>(x, 0L, Dm, Wk, (long)Dm * DH, Kb, (long)T * DH, DH, Dm);
        gemm_n64<<<g, 256, 0, stream>>>(x, 0L, Dm, Wv, (long)Dm * DH, Vb, (long)T * DH, DH, Dm);
    }

    // Fused flash attention for y of ALL heads (S never materialized)
    flash_kernel<<<dim3(T / 64, NH), 256, 0, stream>>>(Qb, Kb, Vb, Yc, invfreq);

    // Head 15 attention map (second output): score + softmax into d_out
    score_kernel<<<dim3(T/64, T/64, 1), 256, 0, stream>>>(Qb, Kb, attn_out, 0L, 15, invfreq);
    softmax_kernel<<<dim3(T, 1), 256, 0, stream>>>(attn_out, 0L);

    // Output projection: y = Yc @ Wout^T
    gemm_out<<<dim3(Dm / 64, T / 64), 256, 0, stream>>>(Yc, Wout, y_out);
}

// Round 8
// 406.361 us; speedup vs baseline: 6.2131x; 1.7758x over previous
//
#include <hip/hip_runtime.h>
#include <math.h>

constexpr int T  = 2048;
constexpr int Dm = 1024;
constexpr int NH = 16;
constexpr int DH = 64;

typedef unsigned short u16;
typedef short bf16x8 __attribute__((ext_vector_type(8)));
typedef float f32x4 __attribute__((ext_vector_type(4)));

#define MFMA16(a, b, c) __builtin_amdgcn_mfma_f32_16x16x32_bf16((a), (b), (c), 0, 0, 0)

__device__ __forceinline__ float b2f(u16 h) {
    union { unsigned int u; float f; } v; v.u = ((unsigned int)h) << 16; return v.f;
}
__device__ __forceinline__ u16 f2b(float f) {   // RNE fp32->bf16
    union { float f; unsigned int u; } v; v.f = f;
    unsigned int r = v.u + 0x7fffu + ((v.u >> 16) & 1u);
    return (u16)(r >> 16);
}

// ---------------------------------------------------------------------------
// invfreq[c] = 10000^(-(c & ~1)/1024)
// ---------------------------------------------------------------------------
__global__ __launch_bounds__(256) void invfreq_kernel(float* __restrict__ invfreq) {
    int c = blockIdx.x * 256 + threadIdx.x;
    if (c < T) {
        float e = (float)(c & ~1) / (float)Dm;
        invfreq[c] = powf(10000.0f, -e);
    }
}

// ---------------------------------------------------------------------------
// AP bf16 table: AP[t][s] = sin/cos(t * invfreq[s])  (8.4 MB, L3-resident)
// ---------------------------------------------------------------------------
__global__ __launch_bounds__(256) void ap_kernel(const float* __restrict__ invfreq,
                                                 u16* __restrict__ ap) {
    int s = blockIdx.x * 256 + threadIdx.x;
    int t = blockIdx.y;
    float ang = (float)t * invfreq[s];
    float v = (s & 1) ? cosf(ang) : sinf(ang);
    ap[(size_t)t * T + s] = f2b(v);
}

// ---------------------------------------------------------------------------
// fp32 GEMM, N=64 tile (used for V projection). C fp32.
// ---------------------------------------------------------------------------
__global__ __launch_bounds__(256) void gemm_n64(
    const float* __restrict__ Abase, long a_zs, int lda,
    const float* __restrict__ Bbase, long b_zs,
    float* __restrict__ Cbase, long c_zs, int ldc, int Kdim)
{
    __shared__ float As[64][20];
    __shared__ float Bs[16][64];

    const int z = blockIdx.y;
    const float* A = Abase + (long)z * a_zs;
    const float* B = Bbase + (long)z * b_zs;
    float* C = Cbase + (long)z * c_zs;

    const int m0 = blockIdx.x * 64;
    const int tid = threadIdx.x;
    const int tx = tid & 15, ty = tid >> 4;
    const int arow = tid >> 2, aq = (tid & 3) * 4;
    const int bkk = tid >> 4, bq = (tid & 15) * 4;

    float acc[4][4] = {};
    for (int kb = 0; kb < Kdim; kb += 16) {
        float4 av = *(const float4*)(A + (long)(m0 + arow) * lda + kb + aq);
        float4 bv = *(const float4*)(B + (long)(kb + bkk) * 64 + bq);
        *(float4*)&As[arow][aq] = av;
        *(float4*)&Bs[bkk][bq]  = bv;
        __syncthreads();
        #pragma unroll
        for (int kk = 0; kk < 16; ++kk) {
            float a[4];
            #pragma unroll
            for (int i = 0; i < 4; ++i) a[i] = As[ty*4+i][kk];
            float4 b4 = *(const float4*)&Bs[kk][tx*4];
            float b[4] = {b4.x, b4.y, b4.z, b4.w};
            #pragma unroll
            for (int i = 0; i < 4; ++i)
                #pragma unroll
                for (int j = 0; j < 4; ++j)
                    acc[i][j] = fmaf(a[i], b[j], acc[i][j]);
        }
        __syncthreads();
    }
    #pragma unroll
    for (int i = 0; i < 4; ++i) {
        float4 o = make_float4(acc[i][0], acc[i][1], acc[i][2], acc[i][3]);
        *(float4*)(C + (long)(m0 + ty*4 + i) * ldc + tx*4) = o;
    }
}

// ---------------------------------------------------------------------------
// Same GEMM but outputs split-precision bf16: Chi = bf16(c), Clo = bf16(c-Chi)
// Used for Q and K projections (preserves fp32 accuracy across bf16 MFMA).
// ---------------------------------------------------------------------------
__global__ __launch_bounds__(256) void gemm_n64b(
    const float* __restrict__ Abase, long a_zs, int lda,
    const float* __restrict__ Bbase, long b_zs,
    u16* __restrict__ ChiB, u16* __restrict__ CloB, long c_zs, int ldc, int Kdim)
{
    __shared__ float As[64][20];
    __shared__ float Bs[16][64];

    const int z = blockIdx.y;
    const float* A = Abase + (long)z * a_zs;
    const float* B = Bbase + (long)z * b_zs;
    u16* Chi = ChiB + (long)z * c_zs;
    u16* Clo = CloB + (long)z * c_zs;

    const int m0 = blockIdx.x * 64;
    const int tid = threadIdx.x;
    const int tx = tid & 15, ty = tid >> 4;
    const int arow = tid >> 2, aq = (tid & 3) * 4;
    const int bkk = tid >> 4, bq = (tid & 15) * 4;

    float acc[4][4] = {};
    for (int kb = 0; kb < Kdim; kb += 16) {
        float4 av = *(const float4*)(A + (long)(m0 + arow) * lda + kb + aq);
        float4 bv = *(const float4*)(B + (long)(kb + bkk) * 64 + bq);
        *(float4*)&As[arow][aq] = av;
        *(float4*)&Bs[bkk][bq]  = bv;
        __syncthreads();
        #pragma unroll
        for (int kk = 0; kk < 16; ++kk) {
            float a[4];
            #pragma unroll
            for (int i = 0; i < 4; ++i) a[i] = As[ty*4+i][kk];
            float4 b4 = *(const float4*)&Bs[kk][tx*4];
            float b[4] = {b4.x, b4.y, b4.z, b4.w};
            #pragma unroll
            for (int i = 0; i < 4; ++i)
                #pragma unroll
                for (int j = 0; j < 4; ++j)
                    acc[i][j] = fmaf(a[i], b[j], acc[i][j]);
        }
        __syncthreads();
    }
    #pragma unroll
    for (int i = 0; i < 4; ++i) {
        ushort4 hv, lv;
        float f0 = acc[i][0], f1 = acc[i][1], f2 = acc[i][2], f3 = acc[i][3];
        hv.x = f2b(f0); hv.y = f2b(f1); hv.z = f2b(f2); hv.w = f2b(f3);
        lv.x = f2b(f0 - b2f(hv.x)); lv.y = f2b(f1 - b2f(hv.y));
        lv.z = f2b(f2 - b2f(hv.z)); lv.w = f2b(f3 - b2f(hv.w));
        long off = (long)(m0 + ty*4 + i) * ldc + tx*4;
        *(ushort4*)(Chi + off) = hv;
        *(ushort4*)(Clo + off) = lv;
    }
}

// ---------------------------------------------------------------------------
// V transpose + bf16 convert: Vf[h][s][d] fp32 -> Vt[h][d][s] bf16
// ---------------------------------------------------------------------------
__global__ __launch_bounds__(256) void vtrans_kernel(const float* __restrict__ Vf,
                                                     u16* __restrict__ Vt)
{
    __shared__ float Ls[64][65];
    const int h = blockIdx.y, s0 = blockIdx.x * 64;
    const int tid = threadIdx.x;

    #pragma unroll
    for (int it = 0; it < 4; ++it) {
        int idx = it * 256 + tid;
        int sl = idx >> 4, d4 = (idx & 15) * 4;
        float4 v = *(const float4*)(Vf + ((size_t)h * T + s0 + sl) * 64 + d4);
        Ls[d4+0][sl] = v.x; Ls[d4+1][sl] = v.y; Ls[d4+2][sl] = v.z; Ls[d4+3][sl] = v.w;
    }
    __syncthreads();

    const int d = tid >> 2, s16 = (tid & 3) * 16;
    union { u16 u[16]; int4 v[2]; } tmp;
    #pragma unroll
    for (int k = 0; k < 16; ++k) tmp.u[k] = f2b(Ls[d][s16 + k]);
    u16* dst = Vt + ((size_t)h * DH + d) * T + s0 + s16;
    *(int4*)(dst)     = tmp.v[0];
    *(int4*)(dst + 8) = tmp.v[1];
}

// ---------------------------------------------------------------------------
// MFMA flash attention. Block = (head, 64 Q rows), 4 waves (16 rows each).
// Split-precision QK^T (3 MFMAs), bf16 PV. XOR-swizzled LDS (m214 pattern).
// ---------------------------------------------------------------------------
__global__ __launch_bounds__(256) void flash_mfma(
    const u16* __restrict__ Qhi, const u16* __restrict__ Qlo,
    const u16* __restrict__ Khi, const u16* __restrict__ Klo,
    const u16* __restrict__ Vt,  const u16* __restrict__ AP,
    float* __restrict__ Yc)
{
    __shared__ u16 KsH[4096];     // 64 x 64 bf16, swizzled rows (8 KB)
    __shared__ u16 KsL[4096];
    __shared__ u16 Vs[4096];      // Vt tile [d][s-window], swizzled
    __shared__ u16 Ps[4][1024];   // per-wave P tile 16 x 64, swizzled

    const int h = blockIdx.y, t0 = blockIdx.x * 64;
    const int tid = threadIdx.x, w = tid >> 6, lane = tid & 63;
    const int b = lane & 15, a = lane >> 4;

    const size_t hTD = (size_t)h * T * DH;

    // Q fragments in registers (A-frag: row = lane&15, k = (lane>>4)*8 + j)
    const size_t qoff = hTD + (size_t)(t0 + 16*w + b) * DH + a * 8;
    bf16x8 qh[2], ql[2];
    qh[0] = *(const bf16x8*)(Qhi + qoff);
    qh[1] = *(const bf16x8*)(Qhi + qoff + 32);
    ql[0] = *(const bf16x8*)(Qlo + qoff);
    ql[1] = *(const bf16x8*)(Qlo + qoff + 32);

    f32x4 oacc[4];
    float m_run[4], l_run[4];
    #pragma unroll
    for (int i = 0; i < 4; ++i) {
        oacc[i] = (f32x4){0.f, 0.f, 0.f, 0.f};
        m_run[i] = -INFINITY; l_run[i] = 0.f;
    }

    // staging: thread -> (row 0..63, 32B chunk of the 128B row)
    const int srow = tid >> 2, sc16 = (tid & 3) * 16;
    const int swz = (srow & 7) << 4;
    const int sb0 = (srow * 128 + sc16 * 2) ^ swz;
    const int sb1 = (srow * 128 + sc16 * 2 + 16) ^ swz;

    for (int s0 = 0; s0 < T; s0 += 64) {
        __syncthreads();
        {
            const u16* gkh = Khi + hTD + (size_t)(s0 + srow) * DH + sc16;
            const u16* gkl = Klo + hTD + (size_t)(s0 + srow) * DH + sc16;
            const u16* gv  = Vt  + hTD + (size_t)srow * T + s0 + sc16;
            *(int4*)((char*)KsH + sb0) = *(const int4*)gkh;
            *(int4*)((char*)KsH + sb1) = *(const int4*)(gkh + 8);
            *(int4*)((char*)KsL + sb0) = *(const int4*)gkl;
            *(int4*)((char*)KsL + sb1) = *(const int4*)(gkl + 8);
            *(int4*)((char*)Vs  + sb0) = *(const int4*)gv;
            *(int4*)((char*)Vs  + sb1) = *(const int4*)(gv + 8);
        }
        __syncthreads();

        // S = Q K^T  (split precision: qh*kh + qh*kl + ql*kh)
        f32x4 acc[4];
        #pragma unroll
        for (int ct = 0; ct < 4; ++ct) acc[ct] = (f32x4){0.f, 0.f, 0.f, 0.f};
        #pragma unroll
        for (int ct = 0; ct < 4; ++ct) {
            #pragma unroll
            for (int ks = 0; ks < 2; ++ks) {
                int row = 16 * ct + b;
                int byt = (row * 128 + ks * 64 + a * 16) ^ ((row & 7) << 4);
                bf16x8 kh = *(const bf16x8*)((const char*)KsH + byt);
                bf16x8 kl = *(const bf16x8*)((const char*)KsL + byt);
                acc[ct] = MFMA16(qh[ks], kh, acc[ct]);
                acc[ct] = MFMA16(qh[ks], kl, acc[ct]);
                acc[ct] = MFMA16(ql[ks], kh, acc[ct]);
            }
        }

        // + AP bias (C-frag: row = a*4+r, col = b+16ct)
        #pragma unroll
        for (int r = 0; r < 4; ++r) {
            int t = t0 + 16 * w + a * 4 + r;
            const u16* aprow = AP + (size_t)t * T + s0 + b;
            #pragma unroll
            for (int ct = 0; ct < 4; ++ct)
                acc[ct][r] += b2f(aprow[16 * ct]);
        }

        // online softmax (rows live on 16 lanes sharing `a`)
        #pragma unroll
        for (int r = 0; r < 4; ++r) {
            float mx = fmaxf(fmaxf(acc[0][r], acc[1][r]), fmaxf(acc[2][r], acc[3][r]));
            #pragma unroll
            for (int msk = 8; msk > 0; msk >>= 1) mx = fmaxf(mx, __shfl_xor(mx, msk));
            float mnew  = fmaxf(m_run[r], mx);
            float alpha = __expf(m_run[r] - mnew);
            float p0 = __expf(acc[0][r] - mnew);
            float p1 = __expf(acc[1][r] - mnew);
            float p2 = __expf(acc[2][r] - mnew);
            float p3 = __expf(acc[3][r] - mnew);
            float rs = p0 + p1 + p2 + p3;
            #pragma unroll
            for (int msk = 8; msk > 0; msk >>= 1) rs += __shfl_xor(rs, msk);
            l_run[r] = l_run[r] * alpha + rs;
            m_run[r] = mnew;
            oacc[0][r] *= alpha; oacc[1][r] *= alpha;
            oacc[2][r] *= alpha; oacc[3][r] *= alpha;
            // stash P (bf16) into per-wave swizzled LDS
            int rl = a * 4 + r;
            int rbase = rl * 128, rswz = (rl & 7) << 4;
            *(u16*)((char*)Ps[w] + ((rbase + (b       ) * 2) ^ rswz)) = f2b(p0);
            *(u16*)((char*)Ps[w] + ((rbase + (b + 16  ) * 2) ^ rswz)) = f2b(p1);
            *(u16*)((char*)Ps[w] + ((rbase + (b + 32  ) * 2) ^ rswz)) = f2b(p2);
            *(u16*)((char*)Ps[w] + ((rbase + (b + 48  ) * 2) ^ rswz)) = f2b(p3);
        }

        // O += P V   (A-frag of P from LDS, B-frag of V from swizzled Vs)
        bf16x8 pa[2];
        #pragma unroll
        for (int ks = 0; ks < 2; ++ks) {
            int byt = (b * 128 + ks * 64 + a * 16) ^ ((b & 7) << 4);
            pa[ks] = *(const bf16x8*)((const char*)Ps[w] + byt);
        }
        #pragma unroll
        for (int dt = 0; dt < 4; ++dt) {
            #pragma unroll
            for (int ks = 0; ks < 2; ++ks) {
                int row = 16 * dt + b;
                int byt = (row * 128 + ks * 64 + a * 16) ^ ((row & 7) << 4);
                bf16x8 vf = *(const bf16x8*)((const char*)Vs + byt);
                oacc[dt] = MFMA16(pa[ks], vf, oacc[dt]);
            }
        }
    }

    #pragma unroll
    for (int r = 0; r < 4; ++r) {
        float inv = 1.f / l_run[r];
        int t = t0 + 16 * w + a * 4 + r;
        #pragma unroll
        for (int dt = 0; dt < 4; ++dt)
            Yc[(size_t)t * Dm + h * DH + 16 * dt + b] = oacc[dt][r] * inv;
    }
}

// ---------------------------------------------------------------------------
// Head-15 scores (fp32 out, for the attn-map output): reads hi/lo bf16 + AP
// ---------------------------------------------------------------------------
__global__ __launch_bounds__(256) void score_kernel(
    const u16* __restrict__ Qhi, const u16* __restrict__ Qlo,
    const u16* __restrict__ Khi, const u16* __restrict__ Klo,
    float* __restrict__ S, int h, const u16* __restrict__ AP)
{
    __shared__ float Qs[64][65];
    __shared__ float Ks[64][65];

    const size_t hTD = (size_t)h * T * DH;
    const int t0 = blockIdx.y * 64, s0 = blockIdx.x * 64;
    const int tid = threadIdx.x;
    const int tx = tid & 15, ty = tid >> 4;

    #pragma unroll
    for (int it = 0; it < 2; ++it) {
        int idx = it * 256 + tid;
        int row = idx >> 3, q8 = (idx & 7) * 8;
        int4 qh4 = *(const int4*)(Qhi + hTD + (size_t)(t0 + row) * DH + q8);
        int4 ql4 = *(const int4*)(Qlo + hTD + (size_t)(t0 + row) * DH + q8);
        int4 kh4 = *(const int4*)(Khi + hTD + (size_t)(s0 + row) * DH + q8);
        int4 kl4 = *(const int4*)(Klo + hTD + (size_t)(s0 + row) * DH + q8);
        const u16* ph = (const u16*)&qh4; const u16* pl = (const u16*)&ql4;
        const u16* rh = (const u16*)&kh4; const u16* rl = (const u16*)&kl4;
        #pragma unroll
        for (int j = 0; j < 8; ++j) {
            Qs[row][q8 + j] = b2f(ph[j]) + b2f(pl[j]);
            Ks[row][q8 + j] = b2f(rh[j]) + b2f(rl[j]);
        }
    }
    __syncthreads();

    float acc[4][4] = {};
    #pragma unroll 8
    for (int kk = 0; kk < 64; ++kk) {
        float a[4], b[4];
        #pragma unroll
        for (int i = 0; i < 4; ++i) a[i] = Qs[ty*4+i][kk];
        #pragma unroll
        for (int j = 0; j < 4; ++j) b[j] = Ks[tx*4+j][kk];
        #pragma unroll
        for (int i = 0; i < 4; ++i)
            #pragma unroll
            for (int j = 0; j < 4; ++j)
                acc[i][j] = fmaf(a[i], b[j], acc[i][j]);
    }

    #pragma unroll
    for (int i = 0; i < 4; ++i) {
        int t = t0 + ty*4 + i;
        const u16* aprow = AP + (size_t)t * T + s0 + tx*4;
        float o[4];
        #pragma unroll
        for (int j = 0; j < 4; ++j) o[j] = acc[i][j] + b2f(aprow[j]);
        float4 ov = make_float4(o[0], o[1], o[2], o[3]);
        *(float4*)(S + (long)t * T + s0 + tx*4) = ov;
    }
}

// ---------------------------------------------------------------------------
// In-place row softmax (head-15 attn map)
// ---------------------------------------------------------------------------
__global__ __launch_bounds__(256) void softmax_kernel(float* __restrict__ Sbase)
{
    float* S = Sbase + (long)blockIdx.x * T;
    const int tid = threadIdx.x;
    const int wid = tid >> 6, lane = tid & 63;

    float4 v0 = *(const float4*)(S + tid*8);
    float4 v1 = *(const float4*)(S + tid*8 + 4);

    float m = fmaxf(fmaxf(fmaxf(v0.x, v0.y), fmaxf(v0.z, v0.w)),
                    fmaxf(fmaxf(v1.x, v1.y), fmaxf(v1.z, v1.w)));
    #pragma unroll
    for (int o = 32; o > 0; o >>= 1) m = fmaxf(m, __shfl_xor(m, o));

    __shared__ float redm[4];
    __shared__ float reds[4];
    if (lane == 0) redm[wid] = m;
    __syncthreads();
    m = fmaxf(fmaxf(redm[0], redm[1]), fmaxf(redm[2], redm[3]));

    v0.x = expf(v0.x - m); v0.y = expf(v0.y - m); v0.z = expf(v0.z - m); v0.w = expf(v0.w - m);
    v1.x = expf(v1.x - m); v1.y = expf(v1.y - m); v1.z = expf(v1.z - m); v1.w = expf(v1.w - m);

    float s = v0.x + v0.y + v0.z + v0.w + v1.x + v1.y + v1.z + v1.w;
    #pragma unroll
    for (int o = 32; o > 0; o >>= 1) s += __shfl_xor(s, o);
    if (lane == 0) reds[wid] = s;
    __syncthreads();
    s = reds[0] + reds[1] + reds[2] + reds[3];

    float inv = 1.0f / s;
    v0.x *= inv; v0.y *= inv; v0.z *= inv; v0.w *= inv;
    v1.x *= inv; v1.y *= inv; v1.z *= inv; v1.w *= inv;
    *(float4*)(S + tid*8)     = v0;
    *(float4*)(S + tid*8 + 4) = v1;
}

// ---------------------------------------------------------------------------
// y_out = Yc @ Wout^T  (fp32)
// ---------------------------------------------------------------------------
__global__ __launch_bounds__(256) void gemm_out(
    const float* __restrict__ A, const float* __restrict__ Bt,
    float* __restrict__ C)
{
    __shared__ float As[64][20];
    __shared__ float Bs[16][68];

    const int m0 = blockIdx.y * 64, n0 = blockIdx.x * 64;
    const int tid = threadIdx.x;
    const int tx = tid & 15, ty = tid >> 4;
    const int arow = tid >> 2, aq = (tid & 3) * 4;
    const int bn = tid >> 2,  bq = (tid & 3) * 4;

    float acc[4][4] = {};
    for (int kb = 0; kb < Dm; kb += 16) {
        float4 av = *(const float4*)(A  + (long)(m0 + arow) * Dm + kb + aq);
        float4 bv = *(const float4*)(Bt + (long)(n0 + bn)  * Dm + kb + bq);
        *(float4*)&As[arow][aq] = av;
        Bs[bq+0][bn] = bv.x; Bs[bq+1][bn] = bv.y; Bs[bq+2][bn] = bv.z; Bs[bq+3][bn] = bv.w;
        __syncthreads();
        #pragma unroll
        for (int kk = 0; kk < 16; ++kk) {
            float a[4];
            #pragma unroll
            for (int i = 0; i < 4; ++i) a[i] = As[ty*4+i][kk];
            float4 b4 = *(const float4*)&Bs[kk][tx*4];
            float b[4] = {b4.x, b4.y, b4.z, b4.w};
            #pragma unroll
            for (int i = 0; i < 4; ++i)
                #pragma unroll
                for (int j = 0; j < 4; ++j)
                    acc[i][j] = fmaf(a[i], b[j], acc[i][j]);
        }
        __syncthreads();
    }
    #pragma unroll
    for (int i = 0; i < 4; ++i) {
        float4 o = make_float4(acc[i][0], acc[i][1], acc[i][2], acc[i][3]);
        *(float4*)(C + (long)(m0 + ty*4 + i) * Dm + n0 + tx*4) = o;
    }
}

// ---------------------------------------------------------------------------
extern "C" void kernel_launch(void* const* d_in, const int* in_sizes, int n_in,
                              void* d_out, int out_size, void* d_ws, size_t ws_size,
                              hipStream_t stream)
{
    const float* x    = (const float*)d_in[0];   // [T, Dm]
    const float* Wq   = (const float*)d_in[1];   // [NH, Dm, DH]
    const float* Wk   = (const float*)d_in[2];
    const float* Wv   = (const float*)d_in[3];
    const float* Wout = (const float*)d_in[4];   // [Dm, Dm]

    float* out      = (float*)d_out;
    float* y_out    = out;                       // [T, Dm]
    float* attn_out = out + (long)T * Dm;        // [T, T]

    // ws layout (~36.8 MB; ws >= 33.6 MB proven in round 7):
    const size_t NE = (size_t)NH * T * DH;       // 2M elements
    float* ws      = (float*)d_ws;
    float* invfreq = ws;                               // 2048 f (8 KB)
    u16* Qhi = (u16*)(ws + 2048);                      // 4 MB each
    u16* Qlo = Qhi + NE;
    u16* Khi = Qlo + NE;
    u16* Klo = Khi + NE;
    float* VfYc = (float*)(Klo + NE);                  // 8 MB: V fp32, later Yc
    u16* Vt16 = (u16*)(VfYc + (size_t)T * Dm);         // 4 MB
    u16* APt  = Vt16 + NE;                             // 8.4 MB
    (void)ws_size;

    invfreq_kernel<<<dim3(8), dim3(256), 0, stream>>>(invfreq);
    ap_kernel<<<dim3(T/256, T), dim3(256), 0, stream>>>(invfreq, APt);

    // Q, K projections -> split bf16 (hi/lo); V -> fp32 then transposed bf16
    {
        dim3 g(T / 64, NH);
        gemm_n64b<<<g, 256, 0, stream>>>(x, 0L, Dm, Wq, (long)Dm * DH, Qhi, Qlo, (long)T * DH, DH, Dm);
        gemm_n64b<<<g, 256, 0, stream>>>(x, 0L, Dm, Wk, (long)Dm * DH, Khi, Klo, (long)T * DH, DH, Dm);
        gemm_n64<<<g, 256, 0, stream>>>(x, 0L, Dm, Wv, (long)Dm * DH, VfYc, (long)T * DH, DH, Dm);
        vtrans_kernel<<<dim3(T/64, NH), 256, 0, stream>>>(VfYc, Vt16);
    }

    // MFMA flash attention (writes Yc into the now-dead Vf region)
    flash_mfma<<<dim3(T / 64, NH), 256, 0, stream>>>(Qhi, Qlo, Khi, Klo, Vt16, APt, VfYc);

    // Head-15 attention map
    score_kernel<<<dim3(T/64, T/64), 256, 0, stream>>>(Qhi, Qlo, Khi, Klo, attn_out, 15, APt);
    softmax_kernel<<<dim3(T), 256, 0, stream>>>(attn_out);

    // Output projection
    gemm_out<<<dim3(Dm / 64, T / 64), 256, 0, stream>>>(VfYc, Wout, y_out);
}

// Round 9
// 289.190 us; speedup vs baseline: 8.7305x; 1.4052x over previous
//
#include <hip/hip_runtime.h>
#include <math.h>

constexpr int T  = 2048;
constexpr int Dm = 1024;
constexpr int NH = 16;
constexpr int DH = 64;

typedef unsigned short u16;
typedef short bf16x8 __attribute__((ext_vector_type(8)));
typedef float f32x4 __attribute__((ext_vector_type(4)));

#define MFMA16(a, b, c) __builtin_amdgcn_mfma_f32_16x16x32_bf16((a), (b), (c), 0, 0, 0)

__device__ __forceinline__ float b2f(u16 h) {
    union { unsigned int u; float f; } v; v.u = ((unsigned int)h) << 16; return v.f;
}
__device__ __forceinline__ u16 f2b(float f) {   // RNE fp32->bf16
    union { float f; unsigned int u; } v; v.f = f;
    unsigned int r = v.u + 0x7fffu + ((v.u >> 16) & 1u);
    return (u16)(r >> 16);
}

// ---------------------------------------------------------------------------
// invfreq[c] = 10000^(-(c & ~1)/1024)
// ---------------------------------------------------------------------------
__global__ __launch_bounds__(256) void invfreq_kernel(float* __restrict__ invfreq) {
    int c = blockIdx.x * 256 + threadIdx.x;
    if (c < T) {
        float e = (float)(c & ~1) / (float)Dm;
        invfreq[c] = powf(10000.0f, -e);
    }
}

// ---------------------------------------------------------------------------
// AP bf16 table: AP[t][s] = sin/cos(t*invfreq[s]); one sincos per even/odd pair
// ---------------------------------------------------------------------------
__global__ __launch_bounds__(256) void ap_kernel(const float* __restrict__ invfreq,
                                                 u16* __restrict__ ap) {
    int p = blockIdx.x * 256 + threadIdx.x;      // pair index
    int t = blockIdx.y;
    int s = p * 2;
    float sn, cs;
    __sincosf((float)t * invfreq[s], &sn, &cs);
    unsigned int packed = (unsigned int)f2b(sn) | ((unsigned int)f2b(cs) << 16);
    *(unsigned int*)(ap + (size_t)t * T + s) = packed;
}

// ---------------------------------------------------------------------------
// x fp32 -> split bf16 (hi, lo)
// ---------------------------------------------------------------------------
__global__ __launch_bounds__(256) void xsplit_kernel(const float* __restrict__ x,
                                                     u16* __restrict__ xhi,
                                                     u16* __restrict__ xlo) {
    size_t i = ((size_t)blockIdx.x * 256 + threadIdx.x) * 4;
    float4 v = *(const float4*)(x + i);
    ushort4 hv, lv;
    hv.x = f2b(v.x); hv.y = f2b(v.y); hv.z = f2b(v.z); hv.w = f2b(v.w);
    lv.x = f2b(v.x - b2f(hv.x)); lv.y = f2b(v.y - b2f(hv.y));
    lv.z = f2b(v.z - b2f(hv.z)); lv.w = f2b(v.w - b2f(hv.w));
    *(ushort4*)(xhi + i) = hv;
    *(ushort4*)(xlo + i) = lv;
}

// ---------------------------------------------------------------------------
// W[h][k][n] fp32 (k=Dm, n=DH) -> Wt[(z,h)][n][k] bf16   (transpose + convert)
// ---------------------------------------------------------------------------
__global__ __launch_bounds__(256) void wtrans_kernel(
    const float* __restrict__ Wq, const float* __restrict__ Wk,
    const float* __restrict__ Wv, u16* __restrict__ Wt)
{
    const int z = blockIdx.z;
    const float* W = (z == 0) ? Wq : (z == 1) ? Wk : Wv;
    const int h = blockIdx.y, kc = blockIdx.x * 64;
    const int tid = threadIdx.x;

    __shared__ float Ls[64][65];   // [n][k-local]
    #pragma unroll
    for (int it = 0; it < 4; ++it) {
        int idx = it * 256 + tid;
        int kl = idx >> 4, n4 = (idx & 15) * 4;
        float4 v = *(const float4*)(W + ((size_t)h * Dm + kc + kl) * DH + n4);
        Ls[n4+0][kl] = v.x; Ls[n4+1][kl] = v.y; Ls[n4+2][kl] = v.z; Ls[n4+3][kl] = v.w;
    }
    __syncthreads();

    const int n = tid >> 2, k16 = (tid & 3) * 16;
    union { u16 u[16]; int4 v[2]; } tmp;
    #pragma unroll
    for (int j = 0; j < 16; ++j) tmp.u[j] = f2b(Ls[n][k16 + j]);
    u16* dst = Wt + (((size_t)z * NH + h) * DH + n) * Dm + kc + k16;
    *(int4*)(dst)     = tmp.v[0];
    *(int4*)(dst + 8) = tmp.v[1];
}

// ---------------------------------------------------------------------------
// Wout fp32 -> bf16 (same layout [n][k])
// ---------------------------------------------------------------------------
__global__ __launch_bounds__(256) void wout_conv_kernel(const float* __restrict__ W,
                                                        u16* __restrict__ Wb) {
    size_t i = ((size_t)blockIdx.x * 256 + threadIdx.x) * 4;
    float4 v = *(const float4*)(W + i);
    ushort4 hv;
    hv.x = f2b(v.x); hv.y = f2b(v.y); hv.z = f2b(v.z); hv.w = f2b(v.w);
    *(ushort4*)(Wb + i) = hv;
}

// ---------------------------------------------------------------------------
// QKV projection via MFMA. Grid (T/64, NH, 3). z=0:Q z=1:K (split out), z=2:V
// (plain bf16, written transposed [h][d][t]).  A = x (split hi/lo), B = Wt.
// ---------------------------------------------------------------------------
__global__ __launch_bounds__(256) void proj_mfma(
    const u16* __restrict__ xhi, const u16* __restrict__ xlo,
    const u16* __restrict__ Wt,
    u16* __restrict__ Qhi, u16* __restrict__ Qlo,
    u16* __restrict__ Khi, u16* __restrict__ Klo,
    u16* __restrict__ Vt)
{
    const int t0 = blockIdx.x * 64, h = blockIdx.y, z = blockIdx.z;
    const int tid = threadIdx.x, w = tid >> 6, lane = tid & 63;
    const int b = lane & 15, a = lane >> 4;

    const u16* Wb = Wt + ((size_t)z * NH + h) * DH * Dm;   // [n][k]
    const int trow = t0 + 16 * w + b;

    f32x4 acc[4];
    #pragma unroll
    for (int ct = 0; ct < 4; ++ct) acc[ct] = (f32x4){0.f, 0.f, 0.f, 0.f};

    for (int kc = 0; kc < Dm; kc += 64) {
        bf16x8 ah[2], al[2];
        ah[0] = *(const bf16x8*)(xhi + (size_t)trow * Dm + kc + a * 8);
        ah[1] = *(const bf16x8*)(xhi + (size_t)trow * Dm + kc + 32 + a * 8);
        if (z < 2) {
            al[0] = *(const bf16x8*)(xlo + (size_t)trow * Dm + kc + a * 8);
            al[1] = *(const bf16x8*)(xlo + (size_t)trow * Dm + kc + 32 + a * 8);
        }
        #pragma unroll
        for (int ct = 0; ct < 4; ++ct) {
            #pragma unroll
            for (int ks = 0; ks < 2; ++ks) {
                bf16x8 bw = *(const bf16x8*)(Wb + (size_t)(16 * ct + b) * Dm + kc + ks * 32 + a * 8);
                acc[ct] = MFMA16(ah[ks], bw, acc[ct]);
                if (z < 2) acc[ct] = MFMA16(al[ks], bw, acc[ct]);
            }
        }
    }

    if (z == 2) {
        // Vt[h][d][t], d = 16ct+b, t = t0+16w+a*4+r
        #pragma unroll
        for (int ct = 0; ct < 4; ++ct)
            #pragma unroll
            for (int r = 0; r < 4; ++r)
                Vt[((size_t)h * DH + 16 * ct + b) * T + t0 + 16 * w + a * 4 + r] = f2b(acc[ct][r]);
    } else {
        u16* Hi = (z == 0) ? Qhi : Khi;
        u16* Lo = (z == 0) ? Qlo : Klo;
        const size_t base = (size_t)h * T * DH;
        #pragma unroll
        for (int ct = 0; ct < 4; ++ct) {
            #pragma unroll
            for (int r = 0; r < 4; ++r) {
                float f = acc[ct][r];
                u16 hv = f2b(f);
                u16 lv = f2b(f - b2f(hv));
                size_t off = base + (size_t)(t0 + 16 * w + a * 4 + r) * DH + 16 * ct + b;
                Hi[off] = hv; Lo[off] = lv;
            }
        }
    }
}

// ---------------------------------------------------------------------------
// MFMA flash attention (validated r7/r8). Epilogue now writes bf16 Yc.
// ---------------------------------------------------------------------------
__global__ __launch_bounds__(256) void flash_mfma(
    const u16* __restrict__ Qhi, const u16* __restrict__ Qlo,
    const u16* __restrict__ Khi, const u16* __restrict__ Klo,
    const u16* __restrict__ Vt,  const u16* __restrict__ AP,
    u16* __restrict__ Ycb)
{
    __shared__ u16 KsH[4096];
    __shared__ u16 KsL[4096];
    __shared__ u16 Vs[4096];
    __shared__ u16 Ps[4][1024];

    const int h = blockIdx.y, t0 = blockIdx.x * 64;
    const int tid = threadIdx.x, w = tid >> 6, lane = tid & 63;
    const int b = lane & 15, a = lane >> 4;

    const size_t hTD = (size_t)h * T * DH;

    const size_t qoff = hTD + (size_t)(t0 + 16*w + b) * DH + a * 8;
    bf16x8 qh[2], ql[2];
    qh[0] = *(const bf16x8*)(Qhi + qoff);
    qh[1] = *(const bf16x8*)(Qhi + qoff + 32);
    ql[0] = *(const bf16x8*)(Qlo + qoff);
    ql[1] = *(const bf16x8*)(Qlo + qoff + 32);

    f32x4 oacc[4];
    float m_run[4], l_run[4];
    #pragma unroll
    for (int i = 0; i < 4; ++i) {
        oacc[i] = (f32x4){0.f, 0.f, 0.f, 0.f};
        m_run[i] = -INFINITY; l_run[i] = 0.f;
    }

    const int srow = tid >> 2, sc16 = (tid & 3) * 16;
    const int swz = (srow & 7) << 4;
    const int sb0 = (srow * 128 + sc16 * 2) ^ swz;
    const int sb1 = (srow * 128 + sc16 * 2 + 16) ^ swz;

    for (int s0 = 0; s0 < T; s0 += 64) {
        __syncthreads();
        {
            const u16* gkh = Khi + hTD + (size_t)(s0 + srow) * DH + sc16;
            const u16* gkl = Klo + hTD + (size_t)(s0 + srow) * DH + sc16;
            const u16* gv  = Vt  + hTD + (size_t)srow * T + s0 + sc16;
            *(int4*)((char*)KsH + sb0) = *(const int4*)gkh;
            *(int4*)((char*)KsH + sb1) = *(const int4*)(gkh + 8);
            *(int4*)((char*)KsL + sb0) = *(const int4*)gkl;
            *(int4*)((char*)KsL + sb1) = *(const int4*)(gkl + 8);
            *(int4*)((char*)Vs  + sb0) = *(const int4*)gv;
            *(int4*)((char*)Vs  + sb1) = *(const int4*)(gv + 8);
        }
        __syncthreads();

        f32x4 acc[4];
        #pragma unroll
        for (int ct = 0; ct < 4; ++ct) acc[ct] = (f32x4){0.f, 0.f, 0.f, 0.f};
        #pragma unroll
        for (int ct = 0; ct < 4; ++ct) {
            #pragma unroll
            for (int ks = 0; ks < 2; ++ks) {
                int row = 16 * ct + b;
                int byt = (row * 128 + ks * 64 + a * 16) ^ ((row & 7) << 4);
                bf16x8 kh = *(const bf16x8*)((const char*)KsH + byt);
                bf16x8 kl = *(const bf16x8*)((const char*)KsL + byt);
                acc[ct] = MFMA16(qh[ks], kh, acc[ct]);
                acc[ct] = MFMA16(qh[ks], kl, acc[ct]);
                acc[ct] = MFMA16(ql[ks], kh, acc[ct]);
            }
        }

        #pragma unroll
        for (int r = 0; r < 4; ++r) {
            int t = t0 + 16 * w + a * 4 + r;
            const u16* aprow = AP + (size_t)t * T + s0 + b;
            #pragma unroll
            for (int ct = 0; ct < 4; ++ct)
                acc[ct][r] += b2f(aprow[16 * ct]);
        }

        #pragma unroll
        for (int r = 0; r < 4; ++r) {
            float mx = fmaxf(fmaxf(acc[0][r], acc[1][r]), fmaxf(acc[2][r], acc[3][r]));
            #pragma unroll
            for (int msk = 8; msk > 0; msk >>= 1) mx = fmaxf(mx, __shfl_xor(mx, msk));
            float mnew  = fmaxf(m_run[r], mx);
            float alpha = __expf(m_run[r] - mnew);
            float p0 = __expf(acc[0][r] - mnew);
            float p1 = __expf(acc[1][r] - mnew);
            float p2 = __expf(acc[2][r] - mnew);
            float p3 = __expf(acc[3][r] - mnew);
            float rs = p0 + p1 + p2 + p3;
            #pragma unroll
            for (int msk = 8; msk > 0; msk >>= 1) rs += __shfl_xor(rs, msk);
            l_run[r] = l_run[r] * alpha + rs;
            m_run[r] = mnew;
            oacc[0][r] *= alpha; oacc[1][r] *= alpha;
            oacc[2][r] *= alpha; oacc[3][r] *= alpha;
            int rl = a * 4 + r;
            int rbase = rl * 128, rswz = (rl & 7) << 4;
            *(u16*)((char*)Ps[w] + ((rbase + (b     ) * 2) ^ rswz)) = f2b(p0);
            *(u16*)((char*)Ps[w] + ((rbase + (b + 16) * 2) ^ rswz)) = f2b(p1);
            *(u16*)((char*)Ps[w] + ((rbase + (b + 32) * 2) ^ rswz)) = f2b(p2);
            *(u16*)((char*)Ps[w] + ((rbase + (b + 48) * 2) ^ rswz)) = f2b(p3);
        }

        bf16x8 pa[2];
        #pragma unroll
        for (int ks = 0; ks < 2; ++ks) {
            int byt = (b * 128 + ks * 64 + a * 16) ^ ((b & 7) << 4);
            pa[ks] = *(const bf16x8*)((const char*)Ps[w] + byt);
        }
        #pragma unroll
        for (int dt = 0; dt < 4; ++dt) {
            #pragma unroll
            for (int ks = 0; ks < 2; ++ks) {
                int row = 16 * dt + b;
                int byt = (row * 128 + ks * 64 + a * 16) ^ ((row & 7) << 4);
                bf16x8 vf = *(const bf16x8*)((const char*)Vs + byt);
                oacc[dt] = MFMA16(pa[ks], vf, oacc[dt]);
            }
        }
    }

    #pragma unroll
    for (int r = 0; r < 4; ++r) {
        float inv = 1.f / l_run[r];
        int t = t0 + 16 * w + a * 4 + r;
        #pragma unroll
        for (int dt = 0; dt < 4; ++dt)
            Ycb[(size_t)t * Dm + h * DH + 16 * dt + b] = f2b(oacc[dt][r] * inv);
    }
}

// ---------------------------------------------------------------------------
// Head-15 scores via MFMA (split QK) + AP -> fp32 S
// ---------------------------------------------------------------------------
__global__ __launch_bounds__(256) void score_mfma(
    const u16* __restrict__ Qhi, const u16* __restrict__ Qlo,
    const u16* __restrict__ Khi, const u16* __restrict__ Klo,
    const u16* __restrict__ AP, float* __restrict__ S)
{
    __shared__ u16 KsH[4096];
    __shared__ u16 KsL[4096];

    const int h = NH - 1;
    const int s0 = blockIdx.x * 64, t0 = blockIdx.y * 64;
    const int tid = threadIdx.x, w = tid >> 6, lane = tid & 63;
    const int b = lane & 15, a = lane >> 4;
    const size_t hTD = (size_t)h * T * DH;

    {
        const int srow = tid >> 2, sc16 = (tid & 3) * 16;
        const int swz = (srow & 7) << 4;
        const int sb0 = (srow * 128 + sc16 * 2) ^ swz;
        const int sb1 = (srow * 128 + sc16 * 2 + 16) ^ swz;
        const u16* gkh = Khi + hTD + (size_t)(s0 + srow) * DH + sc16;
        const u16* gkl = Klo + hTD + (size_t)(s0 + srow) * DH + sc16;
        *(int4*)((char*)KsH + sb0) = *(const int4*)gkh;
        *(int4*)((char*)KsH + sb1) = *(const int4*)(gkh + 8);
        *(int4*)((char*)KsL + sb0) = *(const int4*)gkl;
        *(int4*)((char*)KsL + sb1) = *(const int4*)(gkl + 8);
    }

    const size_t qoff = hTD + (size_t)(t0 + 16*w + b) * DH + a * 8;
    bf16x8 qh[2], ql[2];
    qh[0] = *(const bf16x8*)(Qhi + qoff);
    qh[1] = *(const bf16x8*)(Qhi + qoff + 32);
    ql[0] = *(const bf16x8*)(Qlo + qoff);
    ql[1] = *(const bf16x8*)(Qlo + qoff + 32);
    __syncthreads();

    f32x4 acc[4];
    #pragma unroll
    for (int ct = 0; ct < 4; ++ct) acc[ct] = (f32x4){0.f, 0.f, 0.f, 0.f};
    #pragma unroll
    for (int ct = 0; ct < 4; ++ct) {
        #pragma unroll
        for (int ks = 0; ks < 2; ++ks) {
            int row = 16 * ct + b;
            int byt = (row * 128 + ks * 64 + a * 16) ^ ((row & 7) << 4);
            bf16x8 kh = *(const bf16x8*)((const char*)KsH + byt);
            bf16x8 kl = *(const bf16x8*)((const char*)KsL + byt);
            acc[ct] = MFMA16(qh[ks], kh, acc[ct]);
            acc[ct] = MFMA16(qh[ks], kl, acc[ct]);
            acc[ct] = MFMA16(ql[ks], kh, acc[ct]);
        }
    }

    #pragma unroll
    for (int r = 0; r < 4; ++r) {
        int t = t0 + 16 * w + a * 4 + r;
        const u16* aprow = AP + (size_t)t * T + s0 + b;
        #pragma unroll
        for (int ct = 0; ct < 4; ++ct)
            S[(size_t)t * T + s0 + 16 * ct + b] = acc[ct][r] + b2f(aprow[16 * ct]);
    }
}

// ---------------------------------------------------------------------------
// In-place row softmax (head-15 attn map)
// ---------------------------------------------------------------------------
__global__ __launch_bounds__(256) void softmax_kernel(float* __restrict__ Sbase)
{
    float* S = Sbase + (long)blockIdx.x * T;
    const int tid = threadIdx.x;
    const int wid = tid >> 6, lane = tid & 63;

    float4 v0 = *(const float4*)(S + tid*8);
    float4 v1 = *(const float4*)(S + tid*8 + 4);

    float m = fmaxf(fmaxf(fmaxf(v0.x, v0.y), fmaxf(v0.z, v0.w)),
                    fmaxf(fmaxf(v1.x, v1.y), fmaxf(v1.z, v1.w)));
    #pragma unroll
    for (int o = 32; o > 0; o >>= 1) m = fmaxf(m, __shfl_xor(m, o));

    __shared__ float redm[4];
    __shared__ float reds[4];
    if (lane == 0) redm[wid] = m;
    __syncthreads();
    m = fmaxf(fmaxf(redm[0], redm[1]), fmaxf(redm[2], redm[3]));

    v0.x = expf(v0.x - m); v0.y = expf(v0.y - m); v0.z = expf(v0.z - m); v0.w = expf(v0.w - m);
    v1.x = expf(v1.x - m); v1.y = expf(v1.y - m); v1.z = expf(v1.z - m); v1.w = expf(v1.w - m);

    float s = v0.x + v0.y + v0.z + v0.w + v1.x + v1.y + v1.z + v1.w;
    #pragma unroll
    for (int o = 32; o > 0; o >>= 1) s += __shfl_xor(s, o);
    if (lane == 0) reds[wid] = s;
    __syncthreads();
    s = reds[0] + reds[1] + reds[2] + reds[3];

    float inv = 1.0f / s;
    v0.x *= inv; v0.y *= inv; v0.z *= inv; v0.w *= inv;
    v1.x *= inv; v1.y *= inv; v1.z *= inv; v1.w *= inv;
    *(float4*)(S + tid*8)     = v0;
    *(float4*)(S + tid*8 + 4) = v1;
}

// ---------------------------------------------------------------------------
// y = Ycb(bf16) @ Woutb(bf16)^T via MFMA, no LDS (operands L2-resident)
// ---------------------------------------------------------------------------
__global__ __launch_bounds__(256) void gemm_out_mfma(
    const u16* __restrict__ Ycb, const u16* __restrict__ Wb,  // Wb: [n][k]
    float* __restrict__ y)
{
    const int n0 = blockIdx.x * 64, t0 = blockIdx.y * 64;
    const int tid = threadIdx.x, w = tid >> 6, lane = tid & 63;
    const int b = lane & 15, a = lane >> 4;
    const int trow = t0 + 16 * w + b;

    f32x4 acc[4];
    #pragma unroll
    for (int ct = 0; ct < 4; ++ct) acc[ct] = (f32x4){0.f, 0.f, 0.f, 0.f};

    for (int kc = 0; kc < Dm; kc += 64) {
        bf16x8 af[2];
        af[0] = *(const bf16x8*)(Ycb + (size_t)trow * Dm + kc + a * 8);
        af[1] = *(const bf16x8*)(Ycb + (size_t)trow * Dm + kc + 32 + a * 8);
        #pragma unroll
        for (int ct = 0; ct < 4; ++ct) {
            #pragma unroll
            for (int ks = 0; ks < 2; ++ks) {
                bf16x8 bw = *(const bf16x8*)(Wb + (size_t)(n0 + 16 * ct + b) * Dm + kc + ks * 32 + a * 8);
                acc[ct] = MFMA16(af[ks], bw, acc[ct]);
            }
        }
    }

    #pragma unroll
    for (int r = 0; r < 4; ++r) {
        int t = t0 + 16 * w + a * 4 + r;
        #pragma unroll
        for (int ct = 0; ct < 4; ++ct)
            y[(size_t)t * Dm + n0 + 16 * ct + b] = acc[ct][r];
    }
}

// ---------------------------------------------------------------------------
extern "C" void kernel_launch(void* const* d_in, const int* in_sizes, int n_in,
                              void* d_out, int out_size, void* d_ws, size_t ws_size,
                              hipStream_t stream)
{
    const float* x    = (const float*)d_in[0];
    const float* Wq   = (const float*)d_in[1];
    const float* Wk   = (const float*)d_in[2];
    const float* Wv   = (const float*)d_in[3];
    const float* Wout = (const float*)d_in[4];

    float* out      = (float*)d_out;
    float* y_out    = out;
    float* attn_out = out + (long)T * Dm;

    // ---- workspace layout (34.5 MB total; 36.4 MB proven available r8) ----
    char* ws = (char*)d_ws;
    const size_t MB = 1024 * 1024;
    float* invfreq = (float*)ws;                       // 8 KB
    u16* Qhi = (u16*)(ws + 8192);                      // 4 MB each
    u16* Qlo = (u16*)(ws + 8192 + 4 * MB);
    u16* Khi = (u16*)(ws + 8192 + 8 * MB);
    u16* Klo = (u16*)(ws + 8192 + 12 * MB);
    u16* Vt  = (u16*)(ws + 8192 + 16 * MB);            // 4 MB
    char* C  = ws + 8192 + 20 * MB;                    // 14.5 MB union region
    // phase 1 (projection build):
    u16* xhi = (u16*)(C);                              // 4 MB
    u16* xlo = (u16*)(C + 4 * MB);                     // 4 MB
    u16* Wtb = (u16*)(C + 8 * MB);                     // 6 MB
    // phase 2 (after proj; x/Wtb dead):
    u16* APt   = (u16*)(C);                            // 8 MB (T*T*2)
    u16* Ycb   = (u16*)(C + 8 * MB);                   // 4 MB
    u16* Woutb = (u16*)(C + 12 * MB);                  // 2 MB
    (void)ws_size;

    invfreq_kernel<<<dim3(8), dim3(256), 0, stream>>>(invfreq);

    // build bf16 operands
    xsplit_kernel<<<dim3((T * Dm / 4) / 256), dim3(256), 0, stream>>>(x, xhi, xlo);
    wtrans_kernel<<<dim3(Dm / 64, NH, 3), dim3(256), 0, stream>>>(Wq, Wk, Wv, Wtb);

    // QKV projections (MFMA): Q,K split bf16; V transposed bf16
    proj_mfma<<<dim3(T / 64, NH, 3), dim3(256), 0, stream>>>(
        xhi, xlo, Wtb, Qhi, Qlo, Khi, Klo, Vt);

    // phase-2 buffers (x/Wtb now dead)
    ap_kernel<<<dim3(T / 512, T), dim3(256), 0, stream>>>(invfreq, APt);
    wout_conv_kernel<<<dim3((Dm * Dm / 4) / 256), dim3(256), 0, stream>>>(Wout, Woutb);

    // flash attention -> Ycb (bf16)
    flash_mfma<<<dim3(T / 64, NH), dim3(256), 0, stream>>>(
        Qhi, Qlo, Khi, Klo, Vt, APt, Ycb);

    // head-15 attention map
    score_mfma<<<dim3(T / 64, T / 64), dim3(256), 0, stream>>>(
        Qhi, Qlo, Khi, Klo, APt, attn_out);
    softmax_kernel<<<dim3(T), dim3(256), 0, stream>>>(attn_out);

    // output projection
    gemm_out_mfma<<<dim3(Dm / 64, T / 64), dim3(256), 0, stream>>>(Ycb, Woutb, y_out);
}

// Round 10
// 195.612 us; speedup vs baseline: 12.9071x; 1.4784x over previous
//
#include <hip/hip_runtime.h>
#include <math.h>

constexpr int T  = 2048;
constexpr int Dm = 1024;
constexpr int NH = 16;
constexpr int DH = 64;

typedef unsigned short u16;
typedef short bf16x8 __attribute__((ext_vector_type(8)));
typedef float f32x4 __attribute__((ext_vector_type(4)));

#define MFMA16(a, b, c) __builtin_amdgcn_mfma_f32_16x16x32_bf16((a), (b), (c), 0, 0, 0)

__device__ __forceinline__ float b2f(u16 h) {
    union { unsigned int u; float f; } v; v.u = ((unsigned int)h) << 16; return v.f;
}
__device__ __forceinline__ u16 f2b(float f) {   // RNE fp32->bf16
    union { float f; unsigned int u; } v; v.f = f;
    unsigned int r = v.u + 0x7fffu + ((v.u >> 16) & 1u);
    return (u16)(r >> 16);
}

// ---------------------------------------------------------------------------
// invfreq[c] = 10000^(-(c & ~1)/1024)
// ---------------------------------------------------------------------------
__global__ __launch_bounds__(256) void invfreq_kernel(float* __restrict__ invfreq) {
    int c = blockIdx.x * 256 + threadIdx.x;
    if (c < T) {
        float e = (float)(c & ~1) / (float)Dm;
        invfreq[c] = powf(10000.0f, -e);
    }
}

// ---------------------------------------------------------------------------
// AP bf16 table: AP[t][s] = sin/cos(t*invfreq[s]); one sincos per pair
// ---------------------------------------------------------------------------
__global__ __launch_bounds__(256) void ap_kernel(const float* __restrict__ invfreq,
                                                 u16* __restrict__ ap) {
    int p = blockIdx.x * 256 + threadIdx.x;
    int t = blockIdx.y;
    int s = p * 2;
    float sn, cs;
    __sincosf((float)t * invfreq[s], &sn, &cs);
    unsigned int packed = (unsigned int)f2b(sn) | ((unsigned int)f2b(cs) << 16);
    *(unsigned int*)(ap + (size_t)t * T + s) = packed;
}

// ---------------------------------------------------------------------------
// x fp32 -> split bf16 (hi, lo)
// ---------------------------------------------------------------------------
__global__ __launch_bounds__(256) void xsplit_kernel(const float* __restrict__ x,
                                                     u16* __restrict__ xhi,
                                                     u16* __restrict__ xlo) {
    size_t i = ((size_t)blockIdx.x * 256 + threadIdx.x) * 4;
    float4 v = *(const float4*)(x + i);
    ushort4 hv, lv;
    hv.x = f2b(v.x); hv.y = f2b(v.y); hv.z = f2b(v.z); hv.w = f2b(v.w);
    lv.x = f2b(v.x - b2f(hv.x)); lv.y = f2b(v.y - b2f(hv.y));
    lv.z = f2b(v.z - b2f(hv.z)); lv.w = f2b(v.w - b2f(hv.w));
    *(ushort4*)(xhi + i) = hv;
    *(ushort4*)(xlo + i) = lv;
}

// ---------------------------------------------------------------------------
// W[h][k][n] fp32 -> Wt[(z,h)][n][k] bf16  (transpose + convert)
// ---------------------------------------------------------------------------
__global__ __launch_bounds__(256) void wtrans_kernel(
    const float* __restrict__ Wq, const float* __restrict__ Wk,
    const float* __restrict__ Wv, u16* __restrict__ Wt)
{
    const int z = blockIdx.z;
    const float* W = (z == 0) ? Wq : (z == 1) ? Wk : Wv;
    const int h = blockIdx.y, kc = blockIdx.x * 64;
    const int tid = threadIdx.x;

    __shared__ float Ls[64][65];
    #pragma unroll
    for (int it = 0; it < 4; ++it) {
        int idx = it * 256 + tid;
        int kl = idx >> 4, n4 = (idx & 15) * 4;
        float4 v = *(const float4*)(W + ((size_t)h * Dm + kc + kl) * DH + n4);
        Ls[n4+0][kl] = v.x; Ls[n4+1][kl] = v.y; Ls[n4+2][kl] = v.z; Ls[n4+3][kl] = v.w;
    }
    __syncthreads();

    const int n = tid >> 2, k16 = (tid & 3) * 16;
    union { u16 u[16]; int4 v[2]; } tmp;
    #pragma unroll
    for (int j = 0; j < 16; ++j) tmp.u[j] = f2b(Ls[n][k16 + j]);
    u16* dst = Wt + (((size_t)z * NH + h) * DH + n) * Dm + kc + k16;
    *(int4*)(dst)     = tmp.v[0];
    *(int4*)(dst + 8) = tmp.v[1];
}

// ---------------------------------------------------------------------------
// Wout fp32 -> bf16
// ---------------------------------------------------------------------------
__global__ __launch_bounds__(256) void wout_conv_kernel(const float* __restrict__ W,
                                                        u16* __restrict__ Wb) {
    size_t i = ((size_t)blockIdx.x * 256 + threadIdx.x) * 4;
    float4 v = *(const float4*)(W + i);
    ushort4 hv;
    hv.x = f2b(v.x); hv.y = f2b(v.y); hv.z = f2b(v.z); hv.w = f2b(v.w);
    *(ushort4*)(Wb + i) = hv;
}

// ---------------------------------------------------------------------------
// Fused QKV projection via MFMA + LDS staging. Block = (64 t-rows, head).
// Computes Q,K (split hi/lo) and V (transposed bf16) in one pass over k.
// LDS: x hi/lo + Wq/Wk/Wv tiles = 5 x 8 KB, all XOR-swizzled (flash pattern).
// ---------------------------------------------------------------------------
__global__ __launch_bounds__(256) void proj_mfma(
    const u16* __restrict__ xhi, const u16* __restrict__ xlo,
    const u16* __restrict__ Wt,
    u16* __restrict__ Qhi, u16* __restrict__ Qlo,
    u16* __restrict__ Khi, u16* __restrict__ Klo,
    u16* __restrict__ Vt)
{
    __shared__ u16 XsH[4096];
    __shared__ u16 XsL[4096];
    __shared__ u16 WsQ[4096];
    __shared__ u16 WsK[4096];
    __shared__ u16 WsV[4096];

    const int t0 = blockIdx.x * 64, h = blockIdx.y;
    const int tid = threadIdx.x, w = tid >> 6, lane = tid & 63;
    const int b = lane & 15, a = lane >> 4;

    const int srow = tid >> 2, sc16 = (tid & 3) * 16;
    const int swz = (srow & 7) << 4;
    const int sb0 = (srow * 128 + sc16 * 2) ^ swz;
    const int sb1 = (srow * 128 + sc16 * 2 + 16) ^ swz;

    const u16* WQb = Wt + ((size_t)0 * NH + h) * DH * Dm;
    const u16* WKb = Wt + ((size_t)1 * NH + h) * DH * Dm;
    const u16* WVb = Wt + ((size_t)2 * NH + h) * DH * Dm;

    f32x4 aq[4], ak[4], av[4];
    #pragma unroll
    for (int ct = 0; ct < 4; ++ct) {
        aq[ct] = (f32x4){0.f, 0.f, 0.f, 0.f};
        ak[ct] = (f32x4){0.f, 0.f, 0.f, 0.f};
        av[ct] = (f32x4){0.f, 0.f, 0.f, 0.f};
    }

    for (int kc = 0; kc < Dm; kc += 64) {
        __syncthreads();
        {
            const u16* gxh = xhi + (size_t)(t0 + srow) * Dm + kc + sc16;
            const u16* gxl = xlo + (size_t)(t0 + srow) * Dm + kc + sc16;
            const u16* gwq = WQb + (size_t)srow * Dm + kc + sc16;
            const u16* gwk = WKb + (size_t)srow * Dm + kc + sc16;
            const u16* gwv = WVb + (size_t)srow * Dm + kc + sc16;
            *(int4*)((char*)XsH + sb0) = *(const int4*)gxh;
            *(int4*)((char*)XsH + sb1) = *(const int4*)(gxh + 8);
            *(int4*)((char*)XsL + sb0) = *(const int4*)gxl;
            *(int4*)((char*)XsL + sb1) = *(const int4*)(gxl + 8);
            *(int4*)((char*)WsQ + sb0) = *(const int4*)gwq;
            *(int4*)((char*)WsQ + sb1) = *(const int4*)(gwq + 8);
            *(int4*)((char*)WsK + sb0) = *(const int4*)gwk;
            *(int4*)((char*)WsK + sb1) = *(const int4*)(gwk + 8);
            *(int4*)((char*)WsV + sb0) = *(const int4*)gwv;
            *(int4*)((char*)WsV + sb1) = *(const int4*)(gwv + 8);
        }
        __syncthreads();

        bf16x8 ah[2], al[2];
        #pragma unroll
        for (int ks = 0; ks < 2; ++ks) {
            int row = 16 * w + b;
            int byt = (row * 128 + ks * 64 + a * 16) ^ ((row & 7) << 4);
            ah[ks] = *(const bf16x8*)((const char*)XsH + byt);
            al[ks] = *(const bf16x8*)((const char*)XsL + byt);
        }
        #pragma unroll
        for (int ct = 0; ct < 4; ++ct) {
            #pragma unroll
            for (int ks = 0; ks < 2; ++ks) {
                int row = 16 * ct + b;
                int byt = (row * 128 + ks * 64 + a * 16) ^ ((row & 7) << 4);
                bf16x8 bq = *(const bf16x8*)((const char*)WsQ + byt);
                bf16x8 bk = *(const bf16x8*)((const char*)WsK + byt);
                bf16x8 bv = *(const bf16x8*)((const char*)WsV + byt);
                aq[ct] = MFMA16(ah[ks], bq, aq[ct]);
                aq[ct] = MFMA16(al[ks], bq, aq[ct]);
                ak[ct] = MFMA16(ah[ks], bk, ak[ct]);
                ak[ct] = MFMA16(al[ks], bk, ak[ct]);
                av[ct] = MFMA16(ah[ks], bv, av[ct]);
            }
        }
    }

    const size_t base = (size_t)h * T * DH;
    #pragma unroll
    for (int ct = 0; ct < 4; ++ct) {
        #pragma unroll
        for (int r = 0; r < 4; ++r) {
            int t = t0 + 16 * w + a * 4 + r;
            size_t off = base + (size_t)t * DH + 16 * ct + b;
            float fq = aq[ct][r];
            u16 qv = f2b(fq);
            Qhi[off] = qv; Qlo[off] = f2b(fq - b2f(qv));
            float fk = ak[ct][r];
            u16 kv = f2b(fk);
            Khi[off] = kv; Klo[off] = f2b(fk - b2f(kv));
            Vt[((size_t)h * DH + 16 * ct + b) * T + t] = f2b(av[ct][r]);
        }
    }
}

// ---------------------------------------------------------------------------
// MFMA flash attention (validated r7/r8). Writes bf16 Yc.
// ---------------------------------------------------------------------------
__global__ __launch_bounds__(256) void flash_mfma(
    const u16* __restrict__ Qhi, const u16* __restrict__ Qlo,
    const u16* __restrict__ Khi, const u16* __restrict__ Klo,
    const u16* __restrict__ Vt,  const u16* __restrict__ AP,
    u16* __restrict__ Ycb)
{
    __shared__ u16 KsH[4096];
    __shared__ u16 KsL[4096];
    __shared__ u16 Vs[4096];
    __shared__ u16 Ps[4][1024];

    const int h = blockIdx.y, t0 = blockIdx.x * 64;
    const int tid = threadIdx.x, w = tid >> 6, lane = tid & 63;
    const int b = lane & 15, a = lane >> 4;

    const size_t hTD = (size_t)h * T * DH;

    const size_t qoff = hTD + (size_t)(t0 + 16*w + b) * DH + a * 8;
    bf16x8 qh[2], ql[2];
    qh[0] = *(const bf16x8*)(Qhi + qoff);
    qh[1] = *(const bf16x8*)(Qhi + qoff + 32);
    ql[0] = *(const bf16x8*)(Qlo + qoff);
    ql[1] = *(const bf16x8*)(Qlo + qoff + 32);

    f32x4 oacc[4];
    float m_run[4], l_run[4];
    #pragma unroll
    for (int i = 0; i < 4; ++i) {
        oacc[i] = (f32x4){0.f, 0.f, 0.f, 0.f};
        m_run[i] = -INFINITY; l_run[i] = 0.f;
    }

    const int srow = tid >> 2, sc16 = (tid & 3) * 16;
    const int swz = (srow & 7) << 4;
    const int sb0 = (srow * 128 + sc16 * 2) ^ swz;
    const int sb1 = (srow * 128 + sc16 * 2 + 16) ^ swz;

    for (int s0 = 0; s0 < T; s0 += 64) {
        __syncthreads();
        {
            const u16* gkh = Khi + hTD + (size_t)(s0 + srow) * DH + sc16;
            const u16* gkl = Klo + hTD + (size_t)(s0 + srow) * DH + sc16;
            const u16* gv  = Vt  + hTD + (size_t)srow * T + s0 + sc16;
            *(int4*)((char*)KsH + sb0) = *(const int4*)gkh;
            *(int4*)((char*)KsH + sb1) = *(const int4*)(gkh + 8);
            *(int4*)((char*)KsL + sb0) = *(const int4*)gkl;
            *(int4*)((char*)KsL + sb1) = *(const int4*)(gkl + 8);
            *(int4*)((char*)Vs  + sb0) = *(const int4*)gv;
            *(int4*)((char*)Vs  + sb1) = *(const int4*)(gv + 8);
        }
        __syncthreads();

        f32x4 acc[4];
        #pragma unroll
        for (int ct = 0; ct < 4; ++ct) acc[ct] = (f32x4){0.f, 0.f, 0.f, 0.f};
        #pragma unroll
        for (int ct = 0; ct < 4; ++ct) {
            #pragma unroll
            for (int ks = 0; ks < 2; ++ks) {
                int row = 16 * ct + b;
                int byt = (row * 128 + ks * 64 + a * 16) ^ ((row & 7) << 4);
                bf16x8 kh = *(const bf16x8*)((const char*)KsH + byt);
                bf16x8 kl = *(const bf16x8*)((const char*)KsL + byt);
                acc[ct] = MFMA16(qh[ks], kh, acc[ct]);
                acc[ct] = MFMA16(qh[ks], kl, acc[ct]);
                acc[ct] = MFMA16(ql[ks], kh, acc[ct]);
            }
        }

        #pragma unroll
        for (int r = 0; r < 4; ++r) {
            int t = t0 + 16 * w + a * 4 + r;
            const u16* aprow = AP + (size_t)t * T + s0 + b;
            #pragma unroll
            for (int ct = 0; ct < 4; ++ct)
                acc[ct][r] += b2f(aprow[16 * ct]);
        }

        #pragma unroll
        for (int r = 0; r < 4; ++r) {
            float mx = fmaxf(fmaxf(acc[0][r], acc[1][r]), fmaxf(acc[2][r], acc[3][r]));
            #pragma unroll
            for (int msk = 8; msk > 0; msk >>= 1) mx = fmaxf(mx, __shfl_xor(mx, msk));
            float mnew  = fmaxf(m_run[r], mx);
            float alpha = __expf(m_run[r] - mnew);
            float p0 = __expf(acc[0][r] - mnew);
            float p1 = __expf(acc[1][r] - mnew);
            float p2 = __expf(acc[2][r] - mnew);
            float p3 = __expf(acc[3][r] - mnew);
            float rs = p0 + p1 + p2 + p3;
            #pragma unroll
            for (int msk = 8; msk > 0; msk >>= 1) rs += __shfl_xor(rs, msk);
            l_run[r] = l_run[r] * alpha + rs;
            m_run[r] = mnew;
            oacc[0][r] *= alpha; oacc[1][r] *= alpha;
            oacc[2][r] *= alpha; oacc[3][r] *= alpha;
            int rl = a * 4 + r;
            int rbase = rl * 128, rswz = (rl & 7) << 4;
            *(u16*)((char*)Ps[w] + ((rbase + (b     ) * 2) ^ rswz)) = f2b(p0);
            *(u16*)((char*)Ps[w] + ((rbase + (b + 16) * 2) ^ rswz)) = f2b(p1);
            *(u16*)((char*)Ps[w] + ((rbase + (b + 32) * 2) ^ rswz)) = f2b(p2);
            *(u16*)((char*)Ps[w] + ((rbase + (b + 48) * 2) ^ rswz)) = f2b(p3);
        }

        bf16x8 pa[2];
        #pragma unroll
        for (int ks = 0; ks < 2; ++ks) {
            int byt = (b * 128 + ks * 64 + a * 16) ^ ((b & 7) << 4);
            pa[ks] = *(const bf16x8*)((const char*)Ps[w] + byt);
        }
        #pragma unroll
        for (int dt = 0; dt < 4; ++dt) {
            #pragma unroll
            for (int ks = 0; ks < 2; ++ks) {
                int row = 16 * dt + b;
                int byt = (row * 128 + ks * 64 + a * 16) ^ ((row & 7) << 4);
                bf16x8 vf = *(const bf16x8*)((const char*)Vs + byt);
                oacc[dt] = MFMA16(pa[ks], vf, oacc[dt]);
            }
        }
    }

    #pragma unroll
    for (int r = 0; r < 4; ++r) {
        float inv = 1.f / l_run[r];
        int t = t0 + 16 * w + a * 4 + r;
        #pragma unroll
        for (int dt = 0; dt < 4; ++dt)
            Ycb[(size_t)t * Dm + h * DH + 16 * dt + b] = f2b(oacc[dt][r] * inv);
    }
}

// ---------------------------------------------------------------------------
// Head-15 scores via MFMA (split QK) + AP -> fp32 S
// ---------------------------------------------------------------------------
__global__ __launch_bounds__(256) void score_mfma(
    const u16* __restrict__ Qhi, const u16* __restrict__ Qlo,
    const u16* __restrict__ Khi, const u16* __restrict__ Klo,
    const u16* __restrict__ AP, float* __restrict__ S)
{
    __shared__ u16 KsH[4096];
    __shared__ u16 KsL[4096];

    const int h = NH - 1;
    const int s0 = blockIdx.x * 64, t0 = blockIdx.y * 64;
    const int tid = threadIdx.x, w = tid >> 6, lane = tid & 63;
    const int b = lane & 15, a = lane >> 4;
    const size_t hTD = (size_t)h * T * DH;

    {
        const int srow = tid >> 2, sc16 = (tid & 3) * 16;
        const int swz = (srow & 7) << 4;
        const int sb0 = (srow * 128 + sc16 * 2) ^ swz;
        const int sb1 = (srow * 128 + sc16 * 2 + 16) ^ swz;
        const u16* gkh = Khi + hTD + (size_t)(s0 + srow) * DH + sc16;
        const u16* gkl = Klo + hTD + (size_t)(s0 + srow) * DH + sc16;
        *(int4*)((char*)KsH + sb0) = *(const int4*)gkh;
        *(int4*)((char*)KsH + sb1) = *(const int4*)(gkh + 8);
        *(int4*)((char*)KsL + sb0) = *(const int4*)gkl;
        *(int4*)((char*)KsL + sb1) = *(const int4*)(gkl + 8);
    }

    const size_t qoff = hTD + (size_t)(t0 + 16*w + b) * DH + a * 8;
    bf16x8 qh[2], ql[2];
    qh[0] = *(const bf16x8*)(Qhi + qoff);
    qh[1] = *(const bf16x8*)(Qhi + qoff + 32);
    ql[0] = *(const bf16x8*)(Qlo + qoff);
    ql[1] = *(const bf16x8*)(Qlo + qoff + 32);
    __syncthreads();

    f32x4 acc[4];
    #pragma unroll
    for (int ct = 0; ct < 4; ++ct) acc[ct] = (f32x4){0.f, 0.f, 0.f, 0.f};
    #pragma unroll
    for (int ct = 0; ct < 4; ++ct) {
        #pragma unroll
        for (int ks = 0; ks < 2; ++ks) {
            int row = 16 * ct + b;
            int byt = (row * 128 + ks * 64 + a * 16) ^ ((row & 7) << 4);
            bf16x8 kh = *(const bf16x8*)((const char*)KsH + byt);
            bf16x8 kl = *(const bf16x8*)((const char*)KsL + byt);
            acc[ct] = MFMA16(qh[ks], kh, acc[ct]);
            acc[ct] = MFMA16(qh[ks], kl, acc[ct]);
            acc[ct] = MFMA16(ql[ks], kh, acc[ct]);
        }
    }

    #pragma unroll
    for (int r = 0; r < 4; ++r) {
        int t = t0 + 16 * w + a * 4 + r;
        const u16* aprow = AP + (size_t)t * T + s0 + b;
        #pragma unroll
        for (int ct = 0; ct < 4; ++ct)
            S[(size_t)t * T + s0 + 16 * ct + b] = acc[ct][r] + b2f(aprow[16 * ct]);
    }
}

// ---------------------------------------------------------------------------
// In-place row softmax (head-15 attn map)
// ---------------------------------------------------------------------------
__global__ __launch_bounds__(256) void softmax_kernel(float* __restrict__ Sbase)
{
    float* S = Sbase + (long)blockIdx.x * T;
    const int tid = threadIdx.x;
    const int wid = tid >> 6, lane = tid & 63;

    float4 v0 = *(const float4*)(S + tid*8);
    float4 v1 = *(const float4*)(S + tid*8 + 4);

    float m = fmaxf(fmaxf(fmaxf(v0.x, v0.y), fmaxf(v0.z, v0.w)),
                    fmaxf(fmaxf(v1.x, v1.y), fmaxf(v1.z, v1.w)));
    #pragma unroll
    for (int o = 32; o > 0; o >>= 1) m = fmaxf(m, __shfl_xor(m, o));

    __shared__ float redm[4];
    __shared__ float reds[4];
    if (lane == 0) redm[wid] = m;
    __syncthreads();
    m = fmaxf(fmaxf(redm[0], redm[1]), fmaxf(redm[2], redm[3]));

    v0.x = expf(v0.x - m); v0.y = expf(v0.y - m); v0.z = expf(v0.z - m); v0.w = expf(v0.w - m);
    v1.x = expf(v1.x - m); v1.y = expf(v1.y - m); v1.z = expf(v1.z - m); v1.w = expf(v1.w - m);

    float s = v0.x + v0.y + v0.z + v0.w + v1.x + v1.y + v1.z + v1.w;
    #pragma unroll
    for (int o = 32; o > 0; o >>= 1) s += __shfl_xor(s, o);
    if (lane == 0) reds[wid] = s;
    __syncthreads();
    s = reds[0] + reds[1] + reds[2] + reds[3];

    float inv = 1.0f / s;
    v0.x *= inv; v0.y *= inv; v0.z *= inv; v0.w *= inv;
    v1.x *= inv; v1.y *= inv; v1.z *= inv; v1.w *= inv;
    *(float4*)(S + tid*8)     = v0;
    *(float4*)(S + tid*8 + 4) = v1;
}

// ---------------------------------------------------------------------------
// y = Ycb(bf16) @ Woutb(bf16)^T via MFMA with LDS staging
// ---------------------------------------------------------------------------
__global__ __launch_bounds__(256) void gemm_out_mfma(
    const u16* __restrict__ Ycb, const u16* __restrict__ Wb,  // Wb: [n][k]
    float* __restrict__ y)
{
    __shared__ u16 As[4096];
    __shared__ u16 Bs[4096];

    const int n0 = blockIdx.x * 64, t0 = blockIdx.y * 64;
    const int tid = threadIdx.x, w = tid >> 6, lane = tid & 63;
    const int b = lane & 15, a = lane >> 4;

    const int srow = tid >> 2, sc16 = (tid & 3) * 16;
    const int swz = (srow & 7) << 4;
    const int sb0 = (srow * 128 + sc16 * 2) ^ swz;
    const int sb1 = (srow * 128 + sc16 * 2 + 16) ^ swz;

    f32x4 acc[4];
    #pragma unroll
    for (int ct = 0; ct < 4; ++ct) acc[ct] = (f32x4){0.f, 0.f, 0.f, 0.f};

    for (int kc = 0; kc < Dm; kc += 64) {
        __syncthreads();
        {
            const u16* ga = Ycb + (size_t)(t0 + srow) * Dm + kc + sc16;
            const u16* gb = Wb  + (size_t)(n0 + srow) * Dm + kc + sc16;
            *(int4*)((char*)As + sb0) = *(const int4*)ga;
            *(int4*)((char*)As + sb1) = *(const int4*)(ga + 8);
            *(int4*)((char*)Bs + sb0) = *(const int4*)gb;
            *(int4*)((char*)Bs + sb1) = *(const int4*)(gb + 8);
        }
        __syncthreads();

        bf16x8 af[2];
        #pragma unroll
        for (int ks = 0; ks < 2; ++ks) {
            int row = 16 * w + b;
            int byt = (row * 128 + ks * 64 + a * 16) ^ ((row & 7) << 4);
            af[ks] = *(const bf16x8*)((const char*)As + byt);
        }
        #pragma unroll
        for (int ct = 0; ct < 4; ++ct) {
            #pragma unroll
            for (int ks = 0; ks < 2; ++ks) {
                int row = 16 * ct + b;
                int byt = (row * 128 + ks * 64 + a * 16) ^ ((row & 7) << 4);
                bf16x8 bw = *(const bf16x8*)((const char*)Bs + byt);
                acc[ct] = MFMA16(af[ks], bw, acc[ct]);
            }
        }
    }

    #pragma unroll
    for (int r = 0; r < 4; ++r) {
        int t = t0 + 16 * w + a * 4 + r;
        #pragma unroll
        for (int ct = 0; ct < 4; ++ct)
            y[(size_t)t * Dm + n0 + 16 * ct + b] = acc[ct][r];
    }
}

// ---------------------------------------------------------------------------
extern "C" void kernel_launch(void* const* d_in, const int* in_sizes, int n_in,
                              void* d_out, int out_size, void* d_ws, size_t ws_size,
                              hipStream_t stream)
{
    const float* x    = (const float*)d_in[0];
    const float* Wq   = (const float*)d_in[1];
    const float* Wk   = (const float*)d_in[2];
    const float* Wv   = (const float*)d_in[3];
    const float* Wout = (const float*)d_in[4];

    float* out      = (float*)d_out;
    float* y_out    = out;
    float* attn_out = out + (long)T * Dm;

    // ---- workspace layout (34.5 MB; 36.4 MB proven) ----
    char* ws = (char*)d_ws;
    const size_t MB = 1024 * 1024;
    float* invfreq = (float*)ws;                       // 8 KB
    u16* Qhi = (u16*)(ws + 8192);                      // 4 MB each
    u16* Qlo = (u16*)(ws + 8192 + 4 * MB);
    u16* Khi = (u16*)(ws + 8192 + 8 * MB);
    u16* Klo = (u16*)(ws + 8192 + 12 * MB);
    u16* Vt  = (u16*)(ws + 8192 + 16 * MB);            // 4 MB
    char* C  = ws + 8192 + 20 * MB;                    // 14.5 MB union region
    // phase 1:
    u16* xhi = (u16*)(C);                              // 4 MB
    u16* xlo = (u16*)(C + 4 * MB);                     // 4 MB
    u16* Wtb = (u16*)(C + 8 * MB);                     // 6 MB
    // phase 2 (x/Wtb dead after proj):
    u16* APt   = (u16*)(C);                            // 8 MB
    u16* Ycb   = (u16*)(C + 8 * MB);                   // 4 MB
    u16* Woutb = (u16*)(C + 12 * MB);                  // 2 MB
    (void)ws_size;

    invfreq_kernel<<<dim3(8), dim3(256), 0, stream>>>(invfreq);

    xsplit_kernel<<<dim3((T * Dm / 4) / 256), dim3(256), 0, stream>>>(x, xhi, xlo);
    wtrans_kernel<<<dim3(Dm / 64, NH, 3), dim3(256), 0, stream>>>(Wq, Wk, Wv, Wtb);

    // fused QKV projection (LDS-staged MFMA)
    proj_mfma<<<dim3(T / 64, NH), dim3(256), 0, stream>>>(
        xhi, xlo, Wtb, Qhi, Qlo, Khi, Klo, Vt);

    ap_kernel<<<dim3(T / 512, T), dim3(256), 0, stream>>>(invfreq, APt);
    wout_conv_kernel<<<dim3((Dm * Dm / 4) / 256), dim3(256), 0, stream>>>(Wout, Woutb);

    flash_mfma<<<dim3(T / 64, NH), dim3(256), 0, stream>>>(
        Qhi, Qlo, Khi, Klo, Vt, APt, Ycb);

    score_mfma<<<dim3(T / 64, T / 64), dim3(256), 0, stream>>>(
        Qhi, Qlo, Khi, Klo, APt, attn_out);
    softmax_kernel<<<dim3(T), dim3(256), 0, stream>>>(attn_out);

    gemm_out_mfma<<<dim3(Dm / 64, T / 64), dim3(256), 0, stream>>>(Ycb, Woutb, y_out);
}